// Round 11
// baseline (562.913 us; speedup 1.0000x reference)
//
#include <hip/hip_runtime.h>
#include <hip/hip_bf16.h>
#include <math.h>

#define HD 1024
#define NCLS 10001

typedef short s16x8 __attribute__((ext_vector_type(8)));
typedef unsigned short u16x8 __attribute__((ext_vector_type(8)));
typedef unsigned short u16x4 __attribute__((ext_vector_type(4)));
typedef float f32x4 __attribute__((ext_vector_type(4)));
#define MFMA16(a_, b_, c_) __builtin_amdgcn_mfma_f32_16x16x32_bf16((a_), (b_), (c_), 0, 0, 0)

__device__ __forceinline__ float sigf(float x){ return 1.f/(1.f+__expf(-x)); }
__device__ __forceinline__ float tanhfast(float x){
  x = fminf(fmaxf(x,-10.f),10.f);
  float e2 = __expf(2.f*x);
  return (e2-1.f)/(e2+1.f);
}
__device__ __forceinline__ unsigned short f2bf(float f){
  unsigned int u = __float_as_uint(f);
  u += 0x7FFF + ((u >> 16) & 1);          // round-to-nearest-even
  return (unsigned short)(u >> 16);
}
__device__ __forceinline__ float bf2f(unsigned short u){
  return __uint_as_float(((unsigned)u) << 16);
}
__device__ __forceinline__ u16x8 pack8(float4 a, float4 b){
  u16x8 r;
  r[0]=f2bf(a.x); r[1]=f2bf(a.y); r[2]=f2bf(a.z); r[3]=f2bf(a.w);
  r[4]=f2bf(b.x); r[5]=f2bf(b.y); r[6]=f2bf(b.z); r[7]=f2bf(b.w);
  return r;
}

// ---------------- single merged fp32->bf16 conversion over all weights ----------------
#define CN0 25165824   // W_ih  4*4096*1536
#define CN1 16777216   // W_hh  4*4096*1024
#define CN2 10241024   // W_out 10001*1024
#define CN3 524288     // ann   512*1024
#define CN4 1048576    // W_att 1024*1024
#define CN5 2097152    // W_pre 1024*2048
__global__ __launch_bounds__(256) void k_cvtall(
    const float* __restrict__ Wih, const float* __restrict__ Whh, const float* __restrict__ Wout,
    const float* __restrict__ ann, const float* __restrict__ Watt, const float* __restrict__ Wpre,
    unsigned short* __restrict__ Wbih, unsigned short* __restrict__ Wbhh, unsigned short* __restrict__ Woutb,
    unsigned short* __restrict__ Annb, unsigned short* __restrict__ Wattb,
    unsigned short* __restrict__ Bpre, unsigned short* __restrict__ Wpcb)
{
  unsigned idx = (blockIdx.x*256 + threadIdx.x)*32u;
  const float* src; unsigned short* dst;
  if (idx < CN0) { src = Wih + idx; dst = Wbih + idx; }
  else if ((idx -= CN0) < CN1) { src = Whh + idx; dst = Wbhh + idx; }
  else if ((idx -= CN1) < CN2) { src = Wout + idx; dst = Woutb + idx; }
  else if ((idx -= CN2) < CN3) { src = ann + idx; dst = Annb + idx; }
  else if ((idx -= CN3) < CN4) { src = Watt + idx; dst = Wattb + idx; }
  else if ((idx -= CN4) < CN5) {
    src = Wpre + idx;
    unsigned row = idx >> 11, c = idx & 2047;   // 32-elem group never straddles the 1024 split
    dst = (c < 1024) ? (Bpre + (size_t)row*1536 + c) : (Wpcb + (size_t)row*1024 + (c-1024));
  } else return;
  #pragma unroll
  for (int t = 0; t < 4; ++t) {
    float4 a = *(const float4*)(src + t*8);
    float4 b = *(const float4*)(src + t*8 + 4);
    *(u16x8*)(dst + t*8) = pack8(a,b);
  }
}

// ---------------- emb halves of all LSTM inputs (one-shot; tree topology is static) ----------------
// Xb layout: per level lev in 1..4: XbL = Xb + (lev-1)*4*48*2560; row (slot,j) stride 2560.
__global__ __launch_bounds__(64) void k_emb(const float* __restrict__ emb, const int* __restrict__ values,
                                            unsigned short* __restrict__ Xb){
  int i = blockIdx.x + 1;                  // 1..255
  int lev, s;
  if (i < 5)       { lev=1; s=1; }
  else if (i < 21) { lev=2; s=5; }
  else if (i < 85) { lev=3; s=21; }
  else             { lev=4; s=85; }
  int p = (i-1)>>2, o = i - s;
  unsigned short* xr = Xb + ((size_t)(lev-1)*4*48 + (size_t)(o&3)*48 + (o>>2)) * 2560;
  const float* er = emb + (size_t)values[p]*512;
  int c = threadIdx.x*8;
  float4 a = *(const float4*)(er+c), b = *(const float4*)(er+c+4);
  *(u16x8*)(xr+c) = pack8(a,b);
}

// ---------------- root: C, XH h, and h into level-1 child slots ----------------
__global__ __launch_bounds__(256) void k_root(const float* __restrict__ rH, const float* __restrict__ rC,
                                              float* __restrict__ Cb, unsigned short* __restrict__ XH,
                                              unsigned short* __restrict__ Xb1){
  int u = threadIdx.x*4;
  float4 h = *(const float4*)(rH+u);
  float4 c = *(const float4*)(rC+u);
  *(float4*)(Cb+u) = c;
  u16x4 r; r[0]=f2bf(h.x); r[1]=f2bf(h.y); r[2]=f2bf(h.z); r[3]=f2bf(h.w);
  *(u16x4*)(XH+u) = r;
  #pragma unroll
  for (int k=0;k<4;++k)
    *(u16x4*)(Xb1 + (size_t)k*48*2560 + 1536 + u) = r;
}

// ---------------- full-K bf16 GEMM (AHV / ANWT prep) ----------------
template<int MT>
__global__ __launch_bounds__(256) void k_gemm_fb(
    const unsigned short* __restrict__ A, int astride,
    const unsigned short* __restrict__ B, int K,
    const float* __restrict__ bias,
    unsigned short* __restrict__ Cb16,
    int ostride, int coff, int N, int M)
{
  const int mb0 = blockIdx.y * (MT*16);
  const int wv = threadIdx.x >> 6, lane = threadIdx.x & 63;
  const int col = (blockIdx.x*4 + wv)*16 + (lane & 15);
  const int colc = min(col, N-1);
  const int khalf = (lane >> 4) * 8;

  f32x4 acc[MT];
  #pragma unroll
  for (int m = 0; m < MT; ++m) acc[m] = (f32x4){0.f,0.f,0.f,0.f};
  int arow[MT];
  #pragma unroll
  for (int m = 0; m < MT; ++m) arow[m] = min(mb0 + m*16 + (lane & 15), M-1);

  #pragma unroll 4
  for (int kk = 0; kk < K; kk += 32) {
    int kb = kk + khalf;
    s16x8 bfv = *(const s16x8*)(B + (size_t)colc*K + kb);
    #pragma unroll
    for (int m = 0; m < MT; ++m) {
      s16x8 af = *(const s16x8*)(A + (size_t)arow[m]*astride + kb);
      acc[m] = MFMA16(af, bfv, acc[m]);
    }
  }

  const int r0 = (lane >> 4) * 4;
  #pragma unroll
  for (int m = 0; m < MT; ++m) {
    #pragma unroll
    for (int q = 0; q < 4; ++q) {
      int row = mb0 + m*16 + r0 + q;
      if (row < M && col < N) {
        float v = acc[m][q] + (bias ? bias[col] : 0.f);
        Cb16[(size_t)row*ostride + col + coff] = f2bf(v);
      }
    }
  }
}

// ---------------- W_out GEMM with LDS-staged B ----------------
__global__ __launch_bounds__(256) void k_wout(
    const unsigned short* __restrict__ A,      // Etb [256][1024]
    const unsigned short* __restrict__ B,      // Woutb [10001][1024] (+ slack after)
    const float* __restrict__ bias,
    unsigned short* __restrict__ Lgb)
{
  __shared__ unsigned short bs[16*1032];
  const int c0 = blockIdx.x*16;
  const int tid = threadIdx.x;
  const unsigned short* src = B + (size_t)c0*1024;
  #pragma unroll
  for (int it = 0; it < 8; ++it) {
    int e = it*2048 + tid*8;
    int row = e >> 10, ck = e & 1023;
    *(u16x8*)(bs + row*1032 + ck) = *(const u16x8*)(src + e);
  }
  __syncthreads();

  const int wv = tid >> 6, lane = tid & 63;
  const int col16 = lane & 15;
  const int khalf = (lane >> 4) * 8;
  const int mb0 = wv * 64;
  const int col = c0 + col16;

  f32x4 acc[4];
  #pragma unroll
  for (int m=0;m<4;++m) acc[m] = (f32x4){0.f,0.f,0.f,0.f};
  int arow[4];
  #pragma unroll
  for (int m=0;m<4;++m) arow[m] = mb0 + m*16 + col16;

  #pragma unroll 8
  for (int kk = 0; kk < 1024; kk += 32) {
    int kb = kk + khalf;
    s16x8 bfv = *(const s16x8*)(bs + col16*1032 + kb);
    #pragma unroll
    for (int m=0;m<4;++m) {
      s16x8 af = *(const s16x8*)(A + (size_t)arow[m]*1024 + kb);
      acc[m] = MFMA16(af, bfv, acc[m]);
    }
  }

  if (col < NCLS) {
    const int r0 = (lane >> 4) * 4;
    float bv = bias[col];
    #pragma unroll
    for (int m=0;m<4;++m) {
      #pragma unroll
      for (int q=0;q<4;++q) {
        int row = mb0 + m*16 + r0 + q;
        Lgb[(size_t)row*NCLS + col] = f2bf(acc[m][q] + bv);
      }
    }
  }
}

// ---------------- split-K + slot-batched bf16 GEMM (LSTM), B split B1|B2 ----------------
template<int MT, int KITER>
__global__ __launch_bounds__(256) void k_gemm_skzb2(
    const unsigned short* __restrict__ A, int astride,
    const unsigned short* __restrict__ B1, int K1,
    const unsigned short* __restrict__ B2, int K2,
    float* __restrict__ P, int N, int Mbase, int Mpad,
    int aZ, int b1Z, int b2Z, int KS)
{
  const int z = blockIdx.z;
  const int M = (Mbase - z + 3) >> 2;
  const unsigned short* Az = A + (size_t)z*aZ;
  const unsigned short* B1z = B1 + (size_t)z*b1Z;
  const unsigned short* B2z = B2 + (size_t)z*b2Z;
  const int ks = blockIdx.y;
  const int k0 = ks * (KITER*32);
  const int wv = threadIdx.x >> 6, lane = threadIdx.x & 63;
  const int col = (blockIdx.x*4 + wv)*16 + (lane & 15);
  const int colc = min(col, N-1);
  const int khalf = (lane >> 4) * 8;

  f32x4 acc[MT];
  #pragma unroll
  for (int m = 0; m < MT; ++m) acc[m] = (f32x4){0.f,0.f,0.f,0.f};
  int arow[MT];
  #pragma unroll
  for (int m = 0; m < MT; ++m) arow[m] = min(m*16 + (lane & 15), M-1);

  #pragma unroll 8
  for (int kk = 0; kk < KITER*32; kk += 32) {
    int kb = k0 + kk + khalf;
    const unsigned short* bp = (kb < K1) ? (B1z + (size_t)colc*K1 + kb)
                                         : (B2z + (size_t)colc*K2 + (kb - K1));
    s16x8 bfv = *(const s16x8*)bp;
    #pragma unroll
    for (int m = 0; m < MT; ++m) {
      s16x8 af = *(const s16x8*)(Az + (size_t)arow[m]*astride + kb);
      acc[m] = MFMA16(af, bfv, acc[m]);
    }
  }

  const int r0 = (lane >> 4) * 4;
  #pragma unroll
  for (int m = 0; m < MT; ++m) {
    #pragma unroll
    for (int q = 0; q < 4; ++q) {
      int row = m*16 + r0 + q;
      if (row < M && col < N)
        P[(((size_t)z*KS + ks)*Mpad + row)*N + col] = acc[m][q];
    }
  }
}

// ---------------- small split-K bf16 GEMM (chunk 128): P[ks][M][N] (et GEMM) ----------------
template<int MT>
__global__ __launch_bounds__(256) void k_gemm_skb(
    const unsigned short* __restrict__ A, int astride,
    const unsigned short* __restrict__ B, int K,
    float* __restrict__ P, int N, int M)
{
  const int ks = blockIdx.y;
  const int k0 = ks * 128;
  const int wv = threadIdx.x >> 6, lane = threadIdx.x & 63;
  const int col = (blockIdx.x*4 + wv)*16 + (lane & 15);
  const int colc = min(col, N-1);
  const int khalf = (lane >> 4) * 8;

  f32x4 acc[MT];
  #pragma unroll
  for (int m = 0; m < MT; ++m) acc[m] = (f32x4){0.f,0.f,0.f,0.f};
  int arow[MT];
  #pragma unroll
  for (int m = 0; m < MT; ++m) arow[m] = min(m*16 + (lane & 15), M-1);

  #pragma unroll
  for (int kk = 0; kk < 128; kk += 32) {
    int kb = k0 + kk + khalf;
    s16x8 bfv = *(const s16x8*)(B + (size_t)colc*K + kb);
    #pragma unroll
    for (int m = 0; m < MT; ++m) {
      s16x8 af = *(const s16x8*)(A + (size_t)arow[m]*astride + kb);
      acc[m] = MFMA16(af, bfv, acc[m]);
    }
  }

  const int r0 = (lane >> 4) * 4;
  #pragma unroll
  for (int m = 0; m < MT; ++m) {
    #pragma unroll
    for (int q = 0; q < 4; ++q) {
      int row = m*16 + r0 + q;
      if (row < M && col < N)
        P[((size_t)ks*M + row)*N + col] = acc[m][q];
    }
  }
}

// ---------------- et reduction: block per row; tanh; write Etb + scatter to children Xb ----------------
__global__ __launch_bounds__(256) void k_red4(const float* __restrict__ P, int KS, int M,
                                              const float* __restrict__ bias,
                                              unsigned short* __restrict__ Etb, int s,
                                              int snext, unsigned short* __restrict__ XbNext)
{
  const int row = blockIdx.x;
  const int col = threadIdx.x*4;
  float4 sum = *(const float4*)(bias + col);
  for (int ks = 0; ks < KS; ++ks) {
    float4 p = *(const float4*)(P + ((size_t)ks*M + row)*1024 + col);
    sum.x += p.x; sum.y += p.y; sum.z += p.z; sum.w += p.w;
  }
  u16x4 r;
  r[0]=f2bf(tanhfast(sum.x)); r[1]=f2bf(tanhfast(sum.y));
  r[2]=f2bf(tanhfast(sum.z)); r[3]=f2bf(tanhfast(sum.w));
  *(u16x4*)(Etb + (size_t)(s+row)*1024 + col) = r;
  if (XbNext) {
    int cbase = 4*(s+row) + 1;
    #pragma unroll
    for (int k=0;k<4;++k) {
      int cn = cbase + k;
      if (cn < 256) {
        int o = cn - snext;
        *(u16x4*)(XbNext + ((size_t)(o&3)*48 + (o>>2))*2560 + 512 + col) = r;
      }
    }
  }
}

// ---------------- fused attention: logits (VALU dot vs AHV) + softmax -> probs in XH ----------------
__global__ __launch_bounds__(256) void k_att(const unsigned short* __restrict__ XH,
                                             const unsigned short* __restrict__ AHVb, int s)
{
  __shared__ float hsh[1024];
  __shared__ float sm[512];
  __shared__ float red[8];
  const int node = s + blockIdx.x;
  const int tid = threadIdx.x, wv = tid>>6, ln = tid&63;
  {
    int c = tid*4;
    u16x4 v = *(const u16x4*)(XH + (size_t)node*1536 + c);
    hsh[c]=bf2f(v[0]); hsh[c+1]=bf2f(v[1]); hsh[c+2]=bf2f(v[2]); hsh[c+3]=bf2f(v[3]);
  }
  __syncthreads();

  {
    const unsigned short* b0 = AHVb + (size_t)tid*1024;
    const unsigned short* b1 = AHVb + (size_t)(tid+256)*1024;
    float a0 = 0.f, a1 = 0.f;
    #pragma unroll 2
    for (int k = 0; k < 1024; k += 8) {
      u16x8 v0 = *(const u16x8*)(b0+k);
      u16x8 v1 = *(const u16x8*)(b1+k);
      #pragma unroll
      for (int j=0;j<8;++j) {
        float hv = hsh[k+j];
        a0 = fmaf(bf2f(v0[j]), hv, a0);
        a1 = fmaf(bf2f(v1[j]), hv, a1);
      }
    }
    sm[tid] = a0; sm[tid+256] = a1;
  }
  __syncthreads();

  float mx = fmaxf(sm[tid], sm[tid+256]);
  #pragma unroll
  for (int o=32;o;o>>=1) mx = fmaxf(mx, __shfl_xor(mx,o,64));
  if (ln==0) red[wv]=mx;
  __syncthreads();
  mx = fmaxf(fmaxf(red[0],red[1]),fmaxf(red[2],red[3]));
  float e0 = __expf(sm[tid]-mx), e1 = __expf(sm[tid+256]-mx);
  float se = e0 + e1;
  #pragma unroll
  for (int o=32;o;o>>=1) se += __shfl_xor(se,o,64);
  if (ln==0) red[wv]=se;
  __syncthreads();
  float invS = 1.f/(red[0]+red[1]+red[2]+red[3]);
  unsigned short* dst = (unsigned short*)(XH + (size_t)node*1536 + 1024);
  dst[tid]     = f2bf(e0*invS);
  dst[tid+256] = f2bf(e1*invS);
}

// ---------------- LSTM epilogue: gates -> h,c; scatter h to children Xb ----------------
__global__ __launch_bounds__(256) void k_epi(const float* __restrict__ P,
                                             const float* __restrict__ b_ih, const float* __restrict__ b_hh,
                                             float* __restrict__ Cb, unsigned short* __restrict__ XH,
                                             int s, int snext, unsigned short* __restrict__ XbNext){
  int i = s + blockIdx.x;
  int slot = (i - s) & 3, j = (i - s) >> 2;
  int p = (i - 1) >> 2;
  const float* bi = b_ih + (size_t)slot*4096;
  const float* bh = b_hh + (size_t)slot*4096;
  const int u = threadIdx.x*4;

  float4 ig, fg, gg, og;
  {
    float4 a, b;
    a = *(const float4*)(bi+u);      b = *(const float4*)(bh+u);      ig = make_float4(a.x+b.x,a.y+b.y,a.z+b.z,a.w+b.w);
    a = *(const float4*)(bi+1024+u); b = *(const float4*)(bh+1024+u); fg = make_float4(a.x+b.x,a.y+b.y,a.z+b.z,a.w+b.w);
    a = *(const float4*)(bi+2048+u); b = *(const float4*)(bh+2048+u); gg = make_float4(a.x+b.x,a.y+b.y,a.z+b.z,a.w+b.w);
    a = *(const float4*)(bi+3072+u); b = *(const float4*)(bh+3072+u); og = make_float4(a.x+b.x,a.y+b.y,a.z+b.z,a.w+b.w);
  }
  #pragma unroll
  for (int ks = 0; ks < 5; ++ks) {
    const float* g = P + (((size_t)slot*5 + ks)*48 + j)*4096;
    float4 a;
    a = *(const float4*)(g+u);      ig.x+=a.x; ig.y+=a.y; ig.z+=a.z; ig.w+=a.w;
    a = *(const float4*)(g+1024+u); fg.x+=a.x; fg.y+=a.y; fg.z+=a.z; fg.w+=a.w;
    a = *(const float4*)(g+2048+u); gg.x+=a.x; gg.y+=a.y; gg.z+=a.z; gg.w+=a.w;
    a = *(const float4*)(g+3072+u); og.x+=a.x; og.y+=a.y; og.z+=a.z; og.w+=a.w;
  }
  float4 cp = *(const float4*)(Cb + (size_t)p*1024 + u);
  float4 cc, hh;
  cc.x = sigf(fg.x)*cp.x + sigf(ig.x)*tanhfast(gg.x); hh.x = sigf(og.x)*tanhfast(cc.x);
  cc.y = sigf(fg.y)*cp.y + sigf(ig.y)*tanhfast(gg.y); hh.y = sigf(og.y)*tanhfast(cc.y);
  cc.z = sigf(fg.z)*cp.z + sigf(ig.z)*tanhfast(gg.z); hh.z = sigf(og.z)*tanhfast(cc.z);
  cc.w = sigf(fg.w)*cp.w + sigf(ig.w)*tanhfast(gg.w); hh.w = sigf(og.w)*tanhfast(cc.w);
  *(float4*)(Cb + (size_t)i*1024 + u) = cc;
  u16x4 r; r[0]=f2bf(hh.x); r[1]=f2bf(hh.y); r[2]=f2bf(hh.z); r[3]=f2bf(hh.w);
  *(u16x4*)(XH + (size_t)i*1536 + u) = r;
  if (XbNext) {
    int cbase = 4*i + 1;
    #pragma unroll
    for (int k=0;k<4;++k) {
      int cn = cbase + k;
      if (cn < 256) {
        int o = cn - snext;
        *(u16x4*)(XbNext + ((size_t)(o&3)*48 + (o>>2))*2560 + 1536 + u) = r;
      }
    }
  }
}

// ---------------- loss per node (bf16 logits) ----------------
__global__ __launch_bounds__(256) void k_loss(const unsigned short* __restrict__ Lgb,
                                              const int* __restrict__ values,
                                              float* __restrict__ Nl)
{
  __shared__ float red[8];
  const int node = blockIdx.x;
  const int tid = threadIdx.x, wv = tid>>6, ln = tid&63;
  const unsigned short* lg = Lgb + (size_t)node*NCLS;

  float m = -1e30f;
  for (int i=tid;i<NCLS;i+=256) m = fmaxf(m, bf2f(lg[i]));
  #pragma unroll
  for (int o=32;o;o>>=1) m = fmaxf(m, __shfl_xor(m,o,64));
  if (ln==0) red[wv]=m;
  __syncthreads();
  m = fmaxf(fmaxf(red[0],red[1]),fmaxf(red[2],red[3]));
  __syncthreads();

  float s = 0.f;
  for (int i=tid;i<NCLS;i+=256) s += __expf(bf2f(lg[i])-m);
  #pragma unroll
  for (int o=32;o;o>>=1) s += __shfl_xor(s,o,64);
  if (ln==0) red[wv]=s;
  __syncthreads();
  s = red[0]+red[1]+red[2]+red[3];
  __syncthreads();
  float invs = 1.f/s;

  float q = 0.f;
  for (int i=tid;i<NCLS;i+=256) q += __expf(__expf(bf2f(lg[i])-m)*invs);
  #pragma unroll
  for (int o=32;o;o>>=1) q += __shfl_xor(q,o,64);
  if (ln==0) red[wv]=q;
  __syncthreads();
  if (tid==0) {
    float qq = red[0]+red[1]+red[2]+red[3];
    int v = values[node];
    float pv = __expf(bf2f(lg[v])-m)*invs;
    float nl = __logf(qq) - pv;
    if (v == NCLS-1) nl *= 0.2f;
    Nl[node] = nl;
  }
}

__global__ __launch_bounds__(256) void k_final(const float* __restrict__ Nl, float* __restrict__ out){
  __shared__ float red[8];
  int tid = threadIdx.x, wv = tid>>6, ln = tid&63;
  float s = Nl[tid];
  #pragma unroll
  for (int o=32;o;o>>=1) s += __shfl_xor(s,o,64);
  if (ln==0) red[wv]=s;
  __syncthreads();
  if (tid==0) out[0] = red[0]+red[1]+red[2]+red[3];
}

static inline void gemm_skb(hipStream_t st, int MT, const unsigned short* A, int astride,
                            const unsigned short* B, int K, float* P, int N, int M)
{
  dim3 grid(N/64, K/128);
  #define SKCASE(MTv) k_gemm_skb<MTv><<<grid, 256, 0, st>>>(A,astride,B,K,P,N,M)
  switch(MT){
    case 1:  SKCASE(1);  break;
    case 4:  SKCASE(4);  break;
    case 11: SKCASE(11); break;
    default: SKCASE(16); break;
  }
  #undef SKCASE
}

extern "C" void kernel_launch(void* const* d_in, const int* in_sizes, int n_in,
                              void* d_out, int out_size, void* d_ws, size_t ws_size,
                              hipStream_t stream)
{
  const float* rootH = (const float*)d_in[0];
  const float* rootC = (const float*)d_in[1];
  const float* ann   = (const float*)d_in[2];
  const int*   values= (const int*)d_in[3];
  const float* emb   = (const float*)d_in[6];
  const float* W_ih  = (const float*)d_in[7];
  const float* W_hh  = (const float*)d_in[8];
  const float* b_ih  = (const float*)d_in[9];
  const float* b_hh  = (const float*)d_in[10];
  const float* W_att = (const float*)d_in[11];
  const float* b_att = (const float*)d_in[12];
  const float* W_pre = (const float*)d_in[13];
  const float* b_pre = (const float*)d_in[14];
  const float* W_out = (const float*)d_in[15];
  const float* b_out = (const float*)d_in[16];

  float* ws = (float*)d_ws;
  float* Cb  = ws; ws += 256*1024;              // fp32 c
  float* Nl  = ws; ws += 256;
  float* PB  = ws; ws += 4*5*48*4096;           // shared split-K partials
  unsigned short* Wbih  = (unsigned short*)ws;  // bf16 [4][4096][1536]
  unsigned short* Wbhh  = Wbih  + (size_t)4*4096*1536;   // bf16 [4][4096][1024]
  unsigned short* Woutb = Wbhh  + (size_t)4*4096*1024;   // bf16 [10001][1024]
  unsigned short* Wattb = Woutb + (size_t)NCLS*1024;     // bf16 [1024][1024] (doubles as k_wout OOB slack)
  unsigned short* Bpre  = Wattb + 1024*1024;    // bf16 [1024][1536] = [W_pre_h | ANWT]
  unsigned short* Wpcb  = Bpre  + 1024*1536;    // bf16 [1024][1024] W_pre ctx half
  unsigned short* AHVb  = Wpcb  + 1024*1024;    // bf16 [512][1024]
  unsigned short* Annb  = AHVb  + 512*1024;     // bf16 [512][1024]
  unsigned short* XH    = Annb  + 512*1024;     // bf16 [256][1536] = [h | probs]
  unsigned short* Etb   = XH    + 256*1536;     // bf16 [256][1024]
  unsigned short* Xb    = Etb   + 256*1024;     // bf16 [4 levels][4][48][2560]
  unsigned short* Lgb   = Xb    + (size_t)4*4*48*2560;   // bf16 [256][10001] logits

  // ---- one-time prep: single merged conversion + emb gather + prep GEMMs + root ----
  k_cvtall<<<6819, 256, 0, stream>>>(W_ih, W_hh, W_out, ann, W_att, W_pre,
                                     Wbih, Wbhh, Woutb, Annb, Wattb, Bpre, Wpcb);
  k_emb   <<<255,  64,  0, stream>>>(emb, values, Xb);
  // AHV = ann @ W_att^T + b_att  (bf16 out)
  k_gemm_fb<4><<<dim3(16,8), 256, 0, stream>>>(Annb, 1024, Wattb, 1024, b_att, AHVb, 1024, 0, 1024, 512);
  // ANWT[out][l] = W_pre_ctx[out]·ann[l] -> Bpre[out][1024:1536]
  k_gemm_fb<4><<<dim3(8,16), 256, 0, stream>>>(Wpcb, 1024, Annb, 1024, nullptr, Bpre, 1536, 1024, 512, 1024);
  k_root<<<1, 256, 0, stream>>>(rootH, rootC, Cb, XH, Xb);

  const int LS[6] = {0,1,5,21,85,256};
  for (int lev=0; lev<5; ++lev){
    int s=LS[lev], e=LS[lev+1], n=e-s;
    unsigned short* XbL = Xb + (size_t)(lev-1)*4*48*2560;       // this level's LSTM input (lev>=1)
    unsigned short* XbN = (lev<4) ? (Xb + (size_t)lev*4*48*2560) : nullptr;  // children's
    int snext = (lev<4) ? LS[lev+1] : 0;
    if (lev>0){
      if (lev==4)
        k_gemm_skzb2<3,16><<<dim3(64,5,4),256,0,stream>>>(XbL, 2560, Wbih, 1536, Wbhh, 1024, PB,
            4096, n, 48, 48*2560, 4096*1536, 4096*1024, 5);
      else
        k_gemm_skzb2<1,16><<<dim3(64,5,4),256,0,stream>>>(XbL, 2560, Wbih, 1536, Wbhh, 1024, PB,
            4096, n, 48, 48*2560, 4096*1536, 4096*1024, 5);
      k_epi<<<n,256,0,stream>>>(PB, b_ih, b_hh, Cb, XH, s, snext, XbN);
    }
    // attention logits + softmax -> probs in XH[.][1024:1536]
    k_att<<<n,256,0,stream>>>(XH, AHVb, s);
    // et = tanh([h|probs] · Bpre^T + b_pre): split-K + per-row reduce (+ scatter to children Xb)
    int mtn = (n+15)/16;
    gemm_skb(stream, mtn, XH + (size_t)s*1536, 1536, Bpre, 1536, PB, 1024, n);
    k_red4<<<n,256,0,stream>>>(PB, 12, n, b_pre, Etb, s, snext, XbN);
  }

  // W_out logits: LDS-staged B, bf16 output
  k_wout<<<626, 256, 0, stream>>>(Etb, Woutb, b_out, Lgb);
  k_loss <<<256,256,0,stream>>>(Lgb, values, Nl);
  k_final<<<1,  256,0,stream>>>(Nl, (float*)d_out);
}

// Round 12
// 418.350 us; speedup vs baseline: 1.3456x; 1.3456x over previous
//
#include <hip/hip_runtime.h>
#include <hip/hip_bf16.h>
#include <math.h>

#define HD 1024
#define NCLS 10001

typedef short s16x8 __attribute__((ext_vector_type(8)));
typedef unsigned short u16x8 __attribute__((ext_vector_type(8)));
typedef unsigned short u16x4 __attribute__((ext_vector_type(4)));
typedef float f32x4 __attribute__((ext_vector_type(4)));
#define MFMA16(a_, b_, c_) __builtin_amdgcn_mfma_f32_16x16x32_bf16((a_), (b_), (c_), 0, 0, 0)

__device__ __forceinline__ float sigf(float x){ return 1.f/(1.f+__expf(-x)); }
__device__ __forceinline__ float tanhfast(float x){
  x = fminf(fmaxf(x,-10.f),10.f);
  float e2 = __expf(2.f*x);
  return (e2-1.f)/(e2+1.f);
}
__device__ __forceinline__ unsigned short f2bf(float f){
  unsigned int u = __float_as_uint(f);
  u += 0x7FFF + ((u >> 16) & 1);          // round-to-nearest-even
  return (unsigned short)(u >> 16);
}
__device__ __forceinline__ float bf2f(unsigned short u){
  return __uint_as_float(((unsigned)u) << 16);
}
__device__ __forceinline__ u16x8 pack8(float4 a, float4 b){
  u16x8 r;
  r[0]=f2bf(a.x); r[1]=f2bf(a.y); r[2]=f2bf(a.z); r[3]=f2bf(a.w);
  r[4]=f2bf(b.x); r[5]=f2bf(b.y); r[6]=f2bf(b.z); r[7]=f2bf(b.w);
  return r;
}

// ---------------- single merged fp32->bf16 conversion, coalesced 8/thread x 4 chunks ----------------
#define CN0 25165824u   // W_ih  4*4096*1536
#define CN1 16777216u   // W_hh  4*4096*1024
#define CN2 10241024u   // W_out 10001*1024
#define CN3 524288u     // ann   512*1024
#define CN4 1048576u    // W_att 1024*1024
#define CN5 2097152u    // W_pre 1024*2048
#define CTOT (CN0+CN1+CN2+CN3+CN4+CN5)   // 55854080
__global__ __launch_bounds__(256) void k_cvtall(
    const float* __restrict__ Wih, const float* __restrict__ Whh, const float* __restrict__ Wout,
    const float* __restrict__ ann, const float* __restrict__ Watt, const float* __restrict__ Wpre,
    unsigned short* __restrict__ Wbih, unsigned short* __restrict__ Wbhh, unsigned short* __restrict__ Woutb,
    unsigned short* __restrict__ Annb, unsigned short* __restrict__ Wattb,
    unsigned short* __restrict__ Bpre, unsigned short* __restrict__ Wpcb)
{
  #pragma unroll
  for (unsigned it = 0; it < 4; ++it) {
    unsigned e = (blockIdx.x*1024u + it*256u + threadIdx.x)*8u;   // coalesced: lanes contiguous
    if (e >= CTOT) return;                                        // monotonic in it -> safe
    unsigned idx = e;
    const float* src; unsigned short* dst;
    if (idx < CN0) { src = Wih + idx; dst = Wbih + idx; }
    else if ((idx -= CN0) < CN1) { src = Whh + idx; dst = Wbhh + idx; }
    else if ((idx -= CN1) < CN2) { src = Wout + idx; dst = Woutb + idx; }
    else if ((idx -= CN2) < CN3) { src = ann + idx; dst = Annb + idx; }
    else if ((idx -= CN3) < CN4) { src = Watt + idx; dst = Wattb + idx; }
    else { idx -= CN4;
      src = Wpre + idx;
      unsigned row = idx >> 11, c = idx & 2047;   // 8-group never straddles the 1024 split
      dst = (c < 1024) ? (Bpre + (size_t)row*1536 + c) : (Wpcb + (size_t)row*1024 + (c-1024));
    }
    float4 a = *(const float4*)src;
    float4 b = *(const float4*)(src+4);
    *(u16x8*)dst = pack8(a,b);
  }
}

// ---------------- emb halves of all LSTM inputs (one-shot; tree topology is static) ----------------
__global__ __launch_bounds__(64) void k_emb(const float* __restrict__ emb, const int* __restrict__ values,
                                            unsigned short* __restrict__ Xb){
  int i = blockIdx.x + 1;                  // 1..255
  int lev, s;
  if (i < 5)       { lev=1; s=1; }
  else if (i < 21) { lev=2; s=5; }
  else if (i < 85) { lev=3; s=21; }
  else             { lev=4; s=85; }
  int p = (i-1)>>2, o = i - s;
  unsigned short* xr = Xb + ((size_t)(lev-1)*4*48 + (size_t)(o&3)*48 + (o>>2)) * 2560;
  const float* er = emb + (size_t)values[p]*512;
  int c = threadIdx.x*8;
  float4 a = *(const float4*)(er+c), b = *(const float4*)(er+c+4);
  *(u16x8*)(xr+c) = pack8(a,b);
}

// ---------------- root: C, XH h, and h into level-1 child slots ----------------
__global__ __launch_bounds__(256) void k_root(const float* __restrict__ rH, const float* __restrict__ rC,
                                              float* __restrict__ Cb, unsigned short* __restrict__ XH,
                                              unsigned short* __restrict__ Xb1){
  int u = threadIdx.x*4;
  float4 h = *(const float4*)(rH+u);
  float4 c = *(const float4*)(rC+u);
  *(float4*)(Cb+u) = c;
  u16x4 r; r[0]=f2bf(h.x); r[1]=f2bf(h.y); r[2]=f2bf(h.z); r[3]=f2bf(h.w);
  *(u16x4*)(XH+u) = r;
  #pragma unroll
  for (int k=0;k<4;++k)
    *(u16x4*)(Xb1 + (size_t)k*48*2560 + 1536 + u) = r;
}

// ---------------- full-K bf16 GEMM (AHV / ANWT prep) ----------------
template<int MT>
__global__ __launch_bounds__(256) void k_gemm_fb(
    const unsigned short* __restrict__ A, int astride,
    const unsigned short* __restrict__ B, int K,
    const float* __restrict__ bias,
    unsigned short* __restrict__ Cb16,
    int ostride, int coff, int N, int M)
{
  const int mb0 = blockIdx.y * (MT*16);
  const int wv = threadIdx.x >> 6, lane = threadIdx.x & 63;
  const int col = (blockIdx.x*4 + wv)*16 + (lane & 15);
  const int colc = min(col, N-1);
  const int khalf = (lane >> 4) * 8;

  f32x4 acc[MT];
  #pragma unroll
  for (int m = 0; m < MT; ++m) acc[m] = (f32x4){0.f,0.f,0.f,0.f};
  int arow[MT];
  #pragma unroll
  for (int m = 0; m < MT; ++m) arow[m] = min(mb0 + m*16 + (lane & 15), M-1);

  #pragma unroll 4
  for (int kk = 0; kk < K; kk += 32) {
    int kb = kk + khalf;
    s16x8 bfv = *(const s16x8*)(B + (size_t)colc*K + kb);
    #pragma unroll
    for (int m = 0; m < MT; ++m) {
      s16x8 af = *(const s16x8*)(A + (size_t)arow[m]*astride + kb);
      acc[m] = MFMA16(af, bfv, acc[m]);
    }
  }

  const int r0 = (lane >> 4) * 4;
  #pragma unroll
  for (int m = 0; m < MT; ++m) {
    #pragma unroll
    for (int q = 0; q < 4; ++q) {
      int row = mb0 + m*16 + r0 + q;
      if (row < M && col < N) {
        float v = acc[m][q] + (bias ? bias[col] : 0.f);
        Cb16[(size_t)row*ostride + col + coff] = f2bf(v);
      }
    }
  }
}

// ---------------- W_out GEMM with LDS-staged B ----------------
__global__ __launch_bounds__(256) void k_wout(
    const unsigned short* __restrict__ A,      // Etb [256][1024]
    const unsigned short* __restrict__ B,      // Woutb [10001][1024] (+ slack after)
    const float* __restrict__ bias,
    unsigned short* __restrict__ Lgb)
{
  __shared__ unsigned short bs[16*1032];
  const int c0 = blockIdx.x*16;
  const int tid = threadIdx.x;
  const unsigned short* src = B + (size_t)c0*1024;
  #pragma unroll
  for (int it = 0; it < 8; ++it) {
    int e = it*2048 + tid*8;
    int row = e >> 10, ck = e & 1023;
    *(u16x8*)(bs + row*1032 + ck) = *(const u16x8*)(src + e);
  }
  __syncthreads();

  const int wv = tid >> 6, lane = tid & 63;
  const int col16 = lane & 15;
  const int khalf = (lane >> 4) * 8;
  const int mb0 = wv * 64;
  const int col = c0 + col16;

  f32x4 acc[4];
  #pragma unroll
  for (int m=0;m<4;++m) acc[m] = (f32x4){0.f,0.f,0.f,0.f};
  int arow[4];
  #pragma unroll
  for (int m=0;m<4;++m) arow[m] = mb0 + m*16 + col16;

  #pragma unroll 8
  for (int kk = 0; kk < 1024; kk += 32) {
    int kb = kk + khalf;
    s16x8 bfv = *(const s16x8*)(bs + col16*1032 + kb);
    #pragma unroll
    for (int m=0;m<4;++m) {
      s16x8 af = *(const s16x8*)(A + (size_t)arow[m]*1024 + kb);
      acc[m] = MFMA16(af, bfv, acc[m]);
    }
  }

  if (col < NCLS) {
    const int r0 = (lane >> 4) * 4;
    float bv = bias[col];
    #pragma unroll
    for (int m=0;m<4;++m) {
      #pragma unroll
      for (int q=0;q<4;++q) {
        int row = mb0 + m*16 + r0 + q;
        Lgb[(size_t)row*NCLS + col] = f2bf(acc[m][q] + bv);
      }
    }
  }
}

// ---------------- split-K + slot-batched bf16 GEMM (LSTM), B split B1|B2 ----------------
template<int MT, int KITER>
__global__ __launch_bounds__(256) void k_gemm_skzb2(
    const unsigned short* __restrict__ A, int astride,
    const unsigned short* __restrict__ B1, int K1,
    const unsigned short* __restrict__ B2, int K2,
    float* __restrict__ P, int N, int Mbase, int Mpad,
    int aZ, int b1Z, int b2Z, int KS)
{
  const int z = blockIdx.z;
  const int M = (Mbase - z + 3) >> 2;
  const unsigned short* Az = A + (size_t)z*aZ;
  const unsigned short* B1z = B1 + (size_t)z*b1Z;
  const unsigned short* B2z = B2 + (size_t)z*b2Z;
  const int ks = blockIdx.y;
  const int k0 = ks * (KITER*32);
  const int wv = threadIdx.x >> 6, lane = threadIdx.x & 63;
  const int col = (blockIdx.x*4 + wv)*16 + (lane & 15);
  const int colc = min(col, N-1);
  const int khalf = (lane >> 4) * 8;

  f32x4 acc[MT];
  #pragma unroll
  for (int m = 0; m < MT; ++m) acc[m] = (f32x4){0.f,0.f,0.f,0.f};
  int arow[MT];
  #pragma unroll
  for (int m = 0; m < MT; ++m) arow[m] = min(m*16 + (lane & 15), M-1);

  #pragma unroll 8
  for (int kk = 0; kk < KITER*32; kk += 32) {
    int kb = k0 + kk + khalf;
    const unsigned short* bp = (kb < K1) ? (B1z + (size_t)colc*K1 + kb)
                                         : (B2z + (size_t)colc*K2 + (kb - K1));
    s16x8 bfv = *(const s16x8*)bp;
    #pragma unroll
    for (int m = 0; m < MT; ++m) {
      s16x8 af = *(const s16x8*)(Az + (size_t)arow[m]*astride + kb);
      acc[m] = MFMA16(af, bfv, acc[m]);
    }
  }

  const int r0 = (lane >> 4) * 4;
  #pragma unroll
  for (int m = 0; m < MT; ++m) {
    #pragma unroll
    for (int q = 0; q < 4; ++q) {
      int row = m*16 + r0 + q;
      if (row < M && col < N)
        P[(((size_t)z*KS + ks)*Mpad + row)*N + col] = acc[m][q];
    }
  }
}

// ---------------- small split-K bf16 GEMM (chunk 128): P[ks][M][N] ----------------
template<int MT>
__global__ __launch_bounds__(256) void k_gemm_skb(
    const unsigned short* __restrict__ A, int astride,
    const unsigned short* __restrict__ B, int K,
    float* __restrict__ P, int N, int M)
{
  const int ks = blockIdx.y;
  const int k0 = ks * 128;
  const int wv = threadIdx.x >> 6, lane = threadIdx.x & 63;
  const int col = (blockIdx.x*4 + wv)*16 + (lane & 15);
  const int colc = min(col, N-1);
  const int khalf = (lane >> 4) * 8;

  f32x4 acc[MT];
  #pragma unroll
  for (int m = 0; m < MT; ++m) acc[m] = (f32x4){0.f,0.f,0.f,0.f};
  int arow[MT];
  #pragma unroll
  for (int m = 0; m < MT; ++m) arow[m] = min(m*16 + (lane & 15), M-1);

  #pragma unroll
  for (int kk = 0; kk < 128; kk += 32) {
    int kb = k0 + kk + khalf;
    s16x8 bfv = *(const s16x8*)(B + (size_t)colc*K + kb);
    #pragma unroll
    for (int m = 0; m < MT; ++m) {
      s16x8 af = *(const s16x8*)(A + (size_t)arow[m]*astride + kb);
      acc[m] = MFMA16(af, bfv, acc[m]);
    }
  }

  const int r0 = (lane >> 4) * 4;
  #pragma unroll
  for (int m = 0; m < MT; ++m) {
    #pragma unroll
    for (int q = 0; q < 4; ++q) {
      int row = m*16 + r0 + q;
      if (row < M && col < N)
        P[((size_t)ks*M + row)*N + col] = acc[m][q];
    }
  }
}

// ---------------- fused split-K sum + softmax over 512 logits -> bf16 probs into XH[.][1024:1536] ----------------
__global__ __launch_bounds__(256) void k_soft(const float* __restrict__ P, int KS, int M,
                                              unsigned short* __restrict__ dst)  // XH + s*1536 + 1024
{
  __shared__ float sm[512];
  __shared__ float red[8];
  const int m = blockIdx.x;
  const int tid = threadIdx.x, wv = tid>>6, ln = tid&63;
  for (int l = tid; l < 512; l += 256) {
    float s = 0.f;
    for (int ks = 0; ks < KS; ++ks) s += P[((size_t)ks*M + m)*512 + l];
    sm[l] = s;
  }
  __syncthreads();
  float mx = -1e30f;
  for (int l=tid; l<512; l+=256) mx = fmaxf(mx, sm[l]);
  #pragma unroll
  for (int o=32;o;o>>=1) mx = fmaxf(mx, __shfl_xor(mx,o,64));
  if (ln==0) red[wv]=mx;
  __syncthreads();
  mx = fmaxf(fmaxf(red[0],red[1]),fmaxf(red[2],red[3]));
  float se = 0.f;
  for (int l=tid; l<512; l+=256){ float ev=__expf(sm[l]-mx); sm[l]=ev; se+=ev; }
  __syncthreads();
  #pragma unroll
  for (int o=32;o;o>>=1) se += __shfl_xor(se,o,64);
  if (ln==0) red[wv]=se;
  __syncthreads();
  float invS = 1.f/(red[0]+red[1]+red[2]+red[3]);
  for (int l=tid; l<512; l+=256) dst[(size_t)m*1536 + l] = f2bf(sm[l]*invS);
}

// ---------------- et reduction: block per row; tanh; write Etb + scatter to children Xb ----------------
__global__ __launch_bounds__(256) void k_red4(const float* __restrict__ P, int KS, int M,
                                              const float* __restrict__ bias,
                                              unsigned short* __restrict__ Etb, int s,
                                              int snext, unsigned short* __restrict__ XbNext)
{
  const int row = blockIdx.x;
  const int col = threadIdx.x*4;
  float4 sum = *(const float4*)(bias + col);
  for (int ks = 0; ks < KS; ++ks) {
    float4 p = *(const float4*)(P + ((size_t)ks*M + row)*1024 + col);
    sum.x += p.x; sum.y += p.y; sum.z += p.z; sum.w += p.w;
  }
  u16x4 r;
  r[0]=f2bf(tanhfast(sum.x)); r[1]=f2bf(tanhfast(sum.y));
  r[2]=f2bf(tanhfast(sum.z)); r[3]=f2bf(tanhfast(sum.w));
  *(u16x4*)(Etb + (size_t)(s+row)*1024 + col) = r;
  if (XbNext) {
    int cbase = 4*(s+row) + 1;
    #pragma unroll
    for (int k=0;k<4;++k) {
      int cn = cbase + k;
      if (cn < 256) {
        int o = cn - snext;
        *(u16x4*)(XbNext + ((size_t)(o&3)*48 + (o>>2))*2560 + 512 + col) = r;
      }
    }
  }
}

// ---------------- LSTM epilogue: gates -> h,c; scatter h to children Xb ----------------
__global__ __launch_bounds__(256) void k_epi(const float* __restrict__ P,
                                             const float* __restrict__ b_ih, const float* __restrict__ b_hh,
                                             float* __restrict__ Cb, unsigned short* __restrict__ XH,
                                             int s, int snext, unsigned short* __restrict__ XbNext){
  int i = s + blockIdx.x;
  int slot = (i - s) & 3, j = (i - s) >> 2;
  int p = (i - 1) >> 2;
  const float* bi = b_ih + (size_t)slot*4096;
  const float* bh = b_hh + (size_t)slot*4096;
  const int u = threadIdx.x*4;

  float4 ig, fg, gg, og;
  {
    float4 a, b;
    a = *(const float4*)(bi+u);      b = *(const float4*)(bh+u);      ig = make_float4(a.x+b.x,a.y+b.y,a.z+b.z,a.w+b.w);
    a = *(const float4*)(bi+1024+u); b = *(const float4*)(bh+1024+u); fg = make_float4(a.x+b.x,a.y+b.y,a.z+b.z,a.w+b.w);
    a = *(const float4*)(bi+2048+u); b = *(const float4*)(bh+2048+u); gg = make_float4(a.x+b.x,a.y+b.y,a.z+b.z,a.w+b.w);
    a = *(const float4*)(bi+3072+u); b = *(const float4*)(bh+3072+u); og = make_float4(a.x+b.x,a.y+b.y,a.z+b.z,a.w+b.w);
  }
  #pragma unroll
  for (int ks = 0; ks < 5; ++ks) {
    const float* g = P + (((size_t)slot*5 + ks)*48 + j)*4096;
    float4 a;
    a = *(const float4*)(g+u);      ig.x+=a.x; ig.y+=a.y; ig.z+=a.z; ig.w+=a.w;
    a = *(const float4*)(g+1024+u); fg.x+=a.x; fg.y+=a.y; fg.z+=a.z; fg.w+=a.w;
    a = *(const float4*)(g+2048+u); gg.x+=a.x; gg.y+=a.y; gg.z+=a.z; gg.w+=a.w;
    a = *(const float4*)(g+3072+u); og.x+=a.x; og.y+=a.y; og.z+=a.z; og.w+=a.w;
  }
  float4 cp = *(const float4*)(Cb + (size_t)p*1024 + u);
  float4 cc, hh;
  cc.x = sigf(fg.x)*cp.x + sigf(ig.x)*tanhfast(gg.x); hh.x = sigf(og.x)*tanhfast(cc.x);
  cc.y = sigf(fg.y)*cp.y + sigf(ig.y)*tanhfast(gg.y); hh.y = sigf(og.y)*tanhfast(cc.y);
  cc.z = sigf(fg.z)*cp.z + sigf(ig.z)*tanhfast(gg.z); hh.z = sigf(og.z)*tanhfast(cc.z);
  cc.w = sigf(fg.w)*cp.w + sigf(ig.w)*tanhfast(gg.w); hh.w = sigf(og.w)*tanhfast(cc.w);
  *(float4*)(Cb + (size_t)i*1024 + u) = cc;
  u16x4 r; r[0]=f2bf(hh.x); r[1]=f2bf(hh.y); r[2]=f2bf(hh.z); r[3]=f2bf(hh.w);
  *(u16x4*)(XH + (size_t)i*1536 + u) = r;
  if (XbNext) {
    int cbase = 4*i + 1;
    #pragma unroll
    for (int k=0;k<4;++k) {
      int cn = cbase + k;
      if (cn < 256) {
        int o = cn - snext;
        *(u16x4*)(XbNext + ((size_t)(o&3)*48 + (o>>2))*2560 + 1536 + u) = r;
      }
    }
  }
}

// ---------------- loss per node (bf16 logits) ----------------
__global__ __launch_bounds__(256) void k_loss(const unsigned short* __restrict__ Lgb,
                                              const int* __restrict__ values,
                                              float* __restrict__ Nl)
{
  __shared__ float red[8];
  const int node = blockIdx.x;
  const int tid = threadIdx.x, wv = tid>>6, ln = tid&63;
  const unsigned short* lg = Lgb + (size_t)node*NCLS;

  float m = -1e30f;
  for (int i=tid;i<NCLS;i+=256) m = fmaxf(m, bf2f(lg[i]));
  #pragma unroll
  for (int o=32;o;o>>=1) m = fmaxf(m, __shfl_xor(m,o,64));
  if (ln==0) red[wv]=m;
  __syncthreads();
  m = fmaxf(fmaxf(red[0],red[1]),fmaxf(red[2],red[3]));
  __syncthreads();

  float s = 0.f;
  for (int i=tid;i<NCLS;i+=256) s += __expf(bf2f(lg[i])-m);
  #pragma unroll
  for (int o=32;o;o>>=1) s += __shfl_xor(s,o,64);
  if (ln==0) red[wv]=s;
  __syncthreads();
  s = red[0]+red[1]+red[2]+red[3];
  __syncthreads();
  float invs = 1.f/s;

  float q = 0.f;
  for (int i=tid;i<NCLS;i+=256) q += __expf(__expf(bf2f(lg[i])-m)*invs);
  #pragma unroll
  for (int o=32;o;o>>=1) q += __shfl_xor(q,o,64);
  if (ln==0) red[wv]=q;
  __syncthreads();
  if (tid==0) {
    float qq = red[0]+red[1]+red[2]+red[3];
    int v = values[node];
    float pv = __expf(bf2f(lg[v])-m)*invs;
    float nl = __logf(qq) - pv;
    if (v == NCLS-1) nl *= 0.2f;
    Nl[node] = nl;
  }
}

__global__ __launch_bounds__(256) void k_final(const float* __restrict__ Nl, float* __restrict__ out){
  __shared__ float red[8];
  int tid = threadIdx.x, wv = tid>>6, ln = tid&63;
  float s = Nl[tid];
  #pragma unroll
  for (int o=32;o;o>>=1) s += __shfl_xor(s,o,64);
  if (ln==0) red[wv]=s;
  __syncthreads();
  if (tid==0) out[0] = red[0]+red[1]+red[2]+red[3];
}

static inline void gemm_skb(hipStream_t st, int MT, const unsigned short* A, int astride,
                            const unsigned short* B, int K, float* P, int N, int M)
{
  dim3 grid(N/64, K/128);
  #define SKCASE(MTv) k_gemm_skb<MTv><<<grid, 256, 0, st>>>(A,astride,B,K,P,N,M)
  switch(MT){
    case 1:  SKCASE(1);  break;
    case 4:  SKCASE(4);  break;
    case 11: SKCASE(11); break;
    default: SKCASE(16); break;
  }
  #undef SKCASE
}

extern "C" void kernel_launch(void* const* d_in, const int* in_sizes, int n_in,
                              void* d_out, int out_size, void* d_ws, size_t ws_size,
                              hipStream_t stream)
{
  const float* rootH = (const float*)d_in[0];
  const float* rootC = (const float*)d_in[1];
  const float* ann   = (const float*)d_in[2];
  const int*   values= (const int*)d_in[3];
  const float* emb   = (const float*)d_in[6];
  const float* W_ih  = (const float*)d_in[7];
  const float* W_hh  = (const float*)d_in[8];
  const float* b_ih  = (const float*)d_in[9];
  const float* b_hh  = (const float*)d_in[10];
  const float* W_att = (const float*)d_in[11];
  const float* b_att = (const float*)d_in[12];
  const float* W_pre = (const float*)d_in[13];
  const float* b_pre = (const float*)d_in[14];
  const float* W_out = (const float*)d_in[15];
  const float* b_out = (const float*)d_in[16];

  float* ws = (float*)d_ws;
  float* Cb  = ws; ws += 256*1024;              // fp32 c
  float* Nl  = ws; ws += 256;
  float* PB  = ws; ws += 4*5*48*4096;           // shared split-K partials
  unsigned short* Wbih  = (unsigned short*)ws;  // bf16 [4][4096][1536]
  unsigned short* Wbhh  = Wbih  + (size_t)4*4096*1536;   // bf16 [4][4096][1024]
  unsigned short* Woutb = Wbhh  + (size_t)4*4096*1024;   // bf16 [10001][1024]
  unsigned short* Wattb = Woutb + (size_t)NCLS*1024;     // bf16 [1024][1024] (doubles as k_wout OOB slack)
  unsigned short* Bpre  = Wattb + 1024*1024;    // bf16 [1024][1536] = [W_pre_h | ANWT]
  unsigned short* Wpcb  = Bpre  + 1024*1536;    // bf16 [1024][1024] W_pre ctx half
  unsigned short* AHVb  = Wpcb  + 1024*1024;    // bf16 [512][1024]
  unsigned short* Annb  = AHVb  + 512*1024;     // bf16 [512][1024]
  unsigned short* XH    = Annb  + 512*1024;     // bf16 [256][1536] = [h | probs]
  unsigned short* Etb   = XH    + 256*1536;     // bf16 [256][1024]
  unsigned short* Xb    = Etb   + 256*1024;     // bf16 [4 levels][4][48][2560]
  unsigned short* Lgb   = Xb    + (size_t)4*4*48*2560;   // bf16 [256][10001] logits

  // ---- one-time prep ----
  k_cvtall<<<(CTOT + 8191)/8192, 256, 0, stream>>>(W_ih, W_hh, W_out, ann, W_att, W_pre,
                                     Wbih, Wbhh, Woutb, Annb, Wattb, Bpre, Wpcb);
  k_emb   <<<255,  64,  0, stream>>>(emb, values, Xb);
  // AHV = ann @ W_att^T + b_att  (bf16 out)
  k_gemm_fb<4><<<dim3(16,8), 256, 0, stream>>>(Annb, 1024, Wattb, 1024, b_att, AHVb, 1024, 0, 1024, 512);
  // ANWT[out][l] = W_pre_ctx[out]·ann[l] -> Bpre[out][1024:1536]
  k_gemm_fb<4><<<dim3(8,16), 256, 0, stream>>>(Wpcb, 1024, Annb, 1024, nullptr, Bpre, 1536, 1024, 512, 1024);
  k_root<<<1, 256, 0, stream>>>(rootH, rootC, Cb, XH, Xb);

  const int LS[6] = {0,1,5,21,85,256};
  for (int lev=0; lev<5; ++lev){
    int s=LS[lev], e=LS[lev+1], n=e-s;
    unsigned short* XbL = Xb + (size_t)(lev-1)*4*48*2560;       // this level's LSTM input (lev>=1)
    unsigned short* XbN = (lev<4) ? (Xb + (size_t)lev*4*48*2560) : nullptr;  // children's
    int snext = (lev<4) ? LS[lev+1] : 0;
    if (lev>0){
      if (lev==4)
        k_gemm_skzb2<3,16><<<dim3(64,5,4),256,0,stream>>>(XbL, 2560, Wbih, 1536, Wbhh, 1024, PB,
            4096, n, 48, 48*2560, 4096*1536, 4096*1024, 5);
      else
        k_gemm_skzb2<1,16><<<dim3(64,5,4),256,0,stream>>>(XbL, 2560, Wbih, 1536, Wbhh, 1024, PB,
            4096, n, 48, 48*2560, 4096*1536, 4096*1024, 5);
      k_epi<<<n,256,0,stream>>>(PB, b_ih, b_hh, Cb, XH, s, snext, XbN);
    }
    int mtn = (n+15)/16;
    // attention logits [n x 512] = h · AHV^T (split-K MFMA) + fused softmax -> probs in XH
    gemm_skb(stream, mtn, XH + (size_t)s*1536, 1536, AHVb, 1024, PB, 512, n);
    k_soft<<<n,256,0,stream>>>(PB, 8, n, XH + (size_t)s*1536 + 1024);
    // et = tanh([h|probs] · Bpre^T + b_pre): split-K + per-row reduce (+ scatter to children Xb)
    gemm_skb(stream, mtn, XH + (size_t)s*1536, 1536, Bpre, 1536, PB, 1024, n);
    k_red4<<<n,256,0,stream>>>(PB, 12, n, b_pre, Etb, s, snext, XbN);
  }

  // W_out logits: LDS-staged B, bf16 output
  k_wout<<<626, 256, 0, stream>>>(Etb, Woutb, b_out, Lgb);
  k_loss <<<256,256,0,stream>>>(Lgb, values, Nl);
  k_final<<<1,  256,0,stream>>>(Nl, (float*)d_out);
}

// Round 13
// 409.658 us; speedup vs baseline: 1.3741x; 1.0212x over previous
//
#include <hip/hip_runtime.h>
#include <hip/hip_bf16.h>
#include <math.h>

#define HD 1024
#define NCLS 10001

typedef short s16x8 __attribute__((ext_vector_type(8)));
typedef unsigned short u16x8 __attribute__((ext_vector_type(8)));
typedef unsigned short u16x4 __attribute__((ext_vector_type(4)));
typedef float f32x4 __attribute__((ext_vector_type(4)));
#define MFMA16(a_, b_, c_) __builtin_amdgcn_mfma_f32_16x16x32_bf16((a_), (b_), (c_), 0, 0, 0)

__device__ __forceinline__ float sigf(float x){ return 1.f/(1.f+__expf(-x)); }
__device__ __forceinline__ float tanhfast(float x){
  x = fminf(fmaxf(x,-10.f),10.f);
  float e2 = __expf(2.f*x);
  return (e2-1.f)/(e2+1.f);
}
__device__ __forceinline__ unsigned short f2bf(float f){
  unsigned int u = __float_as_uint(f);
  u += 0x7FFF + ((u >> 16) & 1);          // round-to-nearest-even
  return (unsigned short)(u >> 16);
}
__device__ __forceinline__ float bf2f(unsigned short u){
  return __uint_as_float(((unsigned)u) << 16);
}
__device__ __forceinline__ u16x8 pack8(float4 a, float4 b){
  u16x8 r;
  r[0]=f2bf(a.x); r[1]=f2bf(a.y); r[2]=f2bf(a.z); r[3]=f2bf(a.w);
  r[4]=f2bf(b.x); r[5]=f2bf(b.y); r[6]=f2bf(b.z); r[7]=f2bf(b.w);
  return r;
}

// ---------------- merged fp32->bf16 conversion (NO W_out) — exact grid, straight-line ----------------
#define CN0 25165824u   // W_ih  4*4096*1536
#define CN1 16777216u   // W_hh  4*4096*1024
#define CN3 524288u     // ann   512*1024
#define CN4 1048576u    // W_att 1024*1024
#define CN5 2097152u    // W_pre 1024*2048
#define CTOT2 (CN0+CN1+CN3+CN4+CN5)   // 45613056 = 5568 blocks * 1024 groups * 8 elems exactly
struct SD { const float* s; unsigned short* d; };
__device__ __forceinline__ SD cvt_resolve(unsigned idx,
    const float* Wih, const float* Whh, const float* ann, const float* Watt, const float* Wpre,
    unsigned short* Wbih, unsigned short* Wbhh, unsigned short* Annb, unsigned short* Wattb,
    unsigned short* Bpre, unsigned short* Wpcb)
{
  SD r;
  if (idx < CN0) { r.s = Wih + idx; r.d = Wbih + idx; return r; }
  idx -= CN0;
  if (idx < CN1) { r.s = Whh + idx; r.d = Wbhh + idx; return r; }
  idx -= CN1;
  if (idx < CN3) { r.s = ann + idx; r.d = Annb + idx; return r; }
  idx -= CN3;
  if (idx < CN4) { r.s = Watt + idx; r.d = Wattb + idx; return r; }
  idx -= CN4;
  r.s = Wpre + idx;
  unsigned row = idx >> 11, c = idx & 2047;   // 8-group never straddles the 1024 split
  r.d = (c < 1024) ? (Bpre + (size_t)row*1536 + c) : (Wpcb + (size_t)row*1024 + (c-1024));
  return r;
}
__global__ __launch_bounds__(256) void k_cvtall(
    const float* __restrict__ Wih, const float* __restrict__ Whh,
    const float* __restrict__ ann, const float* __restrict__ Watt, const float* __restrict__ Wpre,
    unsigned short* __restrict__ Wbih, unsigned short* __restrict__ Wbhh,
    unsigned short* __restrict__ Annb, unsigned short* __restrict__ Wattb,
    unsigned short* __restrict__ Bpre, unsigned short* __restrict__ Wpcb)
{
  unsigned g = blockIdx.x*1024u + threadIdx.x;     // 8-elem group index; chunks at +256*it
  SD p0 = cvt_resolve((g        )*8u, Wih,Whh,ann,Watt,Wpre, Wbih,Wbhh,Annb,Wattb,Bpre,Wpcb);
  SD p1 = cvt_resolve((g +  256u)*8u, Wih,Whh,ann,Watt,Wpre, Wbih,Wbhh,Annb,Wattb,Bpre,Wpcb);
  SD p2 = cvt_resolve((g +  512u)*8u, Wih,Whh,ann,Watt,Wpre, Wbih,Wbhh,Annb,Wattb,Bpre,Wpcb);
  SD p3 = cvt_resolve((g +  768u)*8u, Wih,Whh,ann,Watt,Wpre, Wbih,Wbhh,Annb,Wattb,Bpre,Wpcb);
  float4 a0 = *(const float4*)p0.s, b0 = *(const float4*)(p0.s+4);
  float4 a1 = *(const float4*)p1.s, b1 = *(const float4*)(p1.s+4);
  float4 a2 = *(const float4*)p2.s, b2 = *(const float4*)(p2.s+4);
  float4 a3 = *(const float4*)p3.s, b3 = *(const float4*)(p3.s+4);
  *(u16x8*)p0.d = pack8(a0,b0);
  *(u16x8*)p1.d = pack8(a1,b1);
  *(u16x8*)p2.d = pack8(a2,b2);
  *(u16x8*)p3.d = pack8(a3,b3);
}

// ---------------- emb halves of all LSTM inputs (one-shot; tree topology is static) ----------------
__global__ __launch_bounds__(64) void k_emb(const float* __restrict__ emb, const int* __restrict__ values,
                                            unsigned short* __restrict__ Xb){
  int i = blockIdx.x + 1;                  // 1..255
  int lev, s;
  if (i < 5)       { lev=1; s=1; }
  else if (i < 21) { lev=2; s=5; }
  else if (i < 85) { lev=3; s=21; }
  else             { lev=4; s=85; }
  int p = (i-1)>>2, o = i - s;
  unsigned short* xr = Xb + ((size_t)(lev-1)*4*48 + (size_t)(o&3)*48 + (o>>2)) * 2560;
  const float* er = emb + (size_t)values[p]*512;
  int c = threadIdx.x*8;
  float4 a = *(const float4*)(er+c), b = *(const float4*)(er+c+4);
  *(u16x8*)(xr+c) = pack8(a,b);
}

// ---------------- root: C, XH h, and h into level-1 child slots ----------------
__global__ __launch_bounds__(256) void k_root(const float* __restrict__ rH, const float* __restrict__ rC,
                                              float* __restrict__ Cb, unsigned short* __restrict__ XH,
                                              unsigned short* __restrict__ Xb1){
  int u = threadIdx.x*4;
  float4 h = *(const float4*)(rH+u);
  float4 c = *(const float4*)(rC+u);
  *(float4*)(Cb+u) = c;
  u16x4 r; r[0]=f2bf(h.x); r[1]=f2bf(h.y); r[2]=f2bf(h.z); r[3]=f2bf(h.w);
  *(u16x4*)(XH+u) = r;
  #pragma unroll
  for (int k=0;k<4;++k)
    *(u16x4*)(Xb1 + (size_t)k*48*2560 + 1536 + u) = r;
}

// ---------------- full-K bf16 GEMM (AHV / ANWT prep) ----------------
template<int MT>
__global__ __launch_bounds__(256) void k_gemm_fb(
    const unsigned short* __restrict__ A, int astride,
    const unsigned short* __restrict__ B, int K,
    const float* __restrict__ bias,
    unsigned short* __restrict__ Cb16,
    int ostride, int coff, int N, int M)
{
  const int mb0 = blockIdx.y * (MT*16);
  const int wv = threadIdx.x >> 6, lane = threadIdx.x & 63;
  const int col = (blockIdx.x*4 + wv)*16 + (lane & 15);
  const int colc = min(col, N-1);
  const int khalf = (lane >> 4) * 8;

  f32x4 acc[MT];
  #pragma unroll
  for (int m = 0; m < MT; ++m) acc[m] = (f32x4){0.f,0.f,0.f,0.f};
  int arow[MT];
  #pragma unroll
  for (int m = 0; m < MT; ++m) arow[m] = min(mb0 + m*16 + (lane & 15), M-1);

  #pragma unroll 4
  for (int kk = 0; kk < K; kk += 32) {
    int kb = kk + khalf;
    s16x8 bfv = *(const s16x8*)(B + (size_t)colc*K + kb);
    #pragma unroll
    for (int m = 0; m < MT; ++m) {
      s16x8 af = *(const s16x8*)(A + (size_t)arow[m]*astride + kb);
      acc[m] = MFMA16(af, bfv, acc[m]);
    }
  }

  const int r0 = (lane >> 4) * 4;
  #pragma unroll
  for (int m = 0; m < MT; ++m) {
    #pragma unroll
    for (int q = 0; q < 4; ++q) {
      int row = mb0 + m*16 + r0 + q;
      if (row < M && col < N) {
        float v = acc[m][q] + (bias ? bias[col] : 0.f);
        Cb16[(size_t)row*ostride + col + coff] = f2bf(v);
      }
    }
  }
}

// ---------------- W_out GEMM: fp32 B staged+converted to LDS (row-clamped, no OOB) ----------------
__global__ __launch_bounds__(256) void k_wout(
    const unsigned short* __restrict__ A,      // Etb [256][1024]
    const float* __restrict__ B,               // W_out fp32 [10001][1024]
    const float* __restrict__ bias,
    unsigned short* __restrict__ Lgb)
{
  __shared__ unsigned short bs[16*1032];
  const int c0 = blockIdx.x*16;
  const int tid = threadIdx.x;
  #pragma unroll
  for (int it = 0; it < 8; ++it) {
    int e = it*2048 + tid*8;
    int row = e >> 10, ck = e & 1023;
    int rr = min(c0 + row, NCLS-1);
    const float* sp = B + (size_t)rr*1024 + ck;
    float4 a = *(const float4*)sp, b = *(const float4*)(sp+4);
    *(u16x8*)(bs + row*1032 + ck) = pack8(a,b);
  }
  __syncthreads();

  const int wv = tid >> 6, lane = tid & 63;
  const int col16 = lane & 15;
  const int khalf = (lane >> 4) * 8;
  const int mb0 = wv * 64;
  const int col = c0 + col16;

  f32x4 acc[4];
  #pragma unroll
  for (int m=0;m<4;++m) acc[m] = (f32x4){0.f,0.f,0.f,0.f};
  int arow[4];
  #pragma unroll
  for (int m=0;m<4;++m) arow[m] = mb0 + m*16 + col16;

  #pragma unroll 8
  for (int kk = 0; kk < 1024; kk += 32) {
    int kb = kk + khalf;
    s16x8 bfv = *(const s16x8*)(bs + col16*1032 + kb);
    #pragma unroll
    for (int m=0;m<4;++m) {
      s16x8 af = *(const s16x8*)(A + (size_t)arow[m]*1024 + kb);
      acc[m] = MFMA16(af, bfv, acc[m]);
    }
  }

  if (col < NCLS) {
    const int r0 = (lane >> 4) * 4;
    float bv = bias[col];
    #pragma unroll
    for (int m=0;m<4;++m) {
      #pragma unroll
      for (int q=0;q<4;++q) {
        int row = mb0 + m*16 + r0 + q;
        Lgb[(size_t)row*NCLS + col] = f2bf(acc[m][q] + bv);
      }
    }
  }
}

// ---------------- split-K + slot-batched bf16 GEMM (LSTM), B split B1|B2 ----------------
template<int MT, int KITER>
__global__ __launch_bounds__(256) void k_gemm_skzb2(
    const unsigned short* __restrict__ A, int astride,
    const unsigned short* __restrict__ B1, int K1,
    const unsigned short* __restrict__ B2, int K2,
    float* __restrict__ P, int N, int Mbase, int Mpad,
    int aZ, int b1Z, int b2Z, int KS)
{
  const int z = blockIdx.z;
  const int M = (Mbase - z + 3) >> 2;
  const unsigned short* Az = A + (size_t)z*aZ;
  const unsigned short* B1z = B1 + (size_t)z*b1Z;
  const unsigned short* B2z = B2 + (size_t)z*b2Z;
  const int ks = blockIdx.y;
  const int k0 = ks * (KITER*32);
  const int wv = threadIdx.x >> 6, lane = threadIdx.x & 63;
  const int col = (blockIdx.x*4 + wv)*16 + (lane & 15);
  const int colc = min(col, N-1);
  const int khalf = (lane >> 4) * 8;

  f32x4 acc[MT];
  #pragma unroll
  for (int m = 0; m < MT; ++m) acc[m] = (f32x4){0.f,0.f,0.f,0.f};
  int arow[MT];
  #pragma unroll
  for (int m = 0; m < MT; ++m) arow[m] = min(m*16 + (lane & 15), M-1);

  #pragma unroll 8
  for (int kk = 0; kk < KITER*32; kk += 32) {
    int kb = k0 + kk + khalf;
    const unsigned short* bp = (kb < K1) ? (B1z + (size_t)colc*K1 + kb)
                                         : (B2z + (size_t)colc*K2 + (kb - K1));
    s16x8 bfv = *(const s16x8*)bp;
    #pragma unroll
    for (int m = 0; m < MT; ++m) {
      s16x8 af = *(const s16x8*)(Az + (size_t)arow[m]*astride + kb);
      acc[m] = MFMA16(af, bfv, acc[m]);
    }
  }

  const int r0 = (lane >> 4) * 4;
  #pragma unroll
  for (int m = 0; m < MT; ++m) {
    #pragma unroll
    for (int q = 0; q < 4; ++q) {
      int row = m*16 + r0 + q;
      if (row < M && col < N)
        P[(((size_t)z*KS + ks)*Mpad + row)*N + col] = acc[m][q];
    }
  }
}

// ---------------- small split-K bf16 GEMM (chunk 128): P[ks][M][N] ----------------
template<int MT>
__global__ __launch_bounds__(256) void k_gemm_skb(
    const unsigned short* __restrict__ A, int astride,
    const unsigned short* __restrict__ B, int K,
    float* __restrict__ P, int N, int M)
{
  const int ks = blockIdx.y;
  const int k0 = ks * 128;
  const int wv = threadIdx.x >> 6, lane = threadIdx.x & 63;
  const int col = (blockIdx.x*4 + wv)*16 + (lane & 15);
  const int colc = min(col, N-1);
  const int khalf = (lane >> 4) * 8;

  f32x4 acc[MT];
  #pragma unroll
  for (int m = 0; m < MT; ++m) acc[m] = (f32x4){0.f,0.f,0.f,0.f};
  int arow[MT];
  #pragma unroll
  for (int m = 0; m < MT; ++m) arow[m] = min(m*16 + (lane & 15), M-1);

  #pragma unroll
  for (int kk = 0; kk < 128; kk += 32) {
    int kb = k0 + kk + khalf;
    s16x8 bfv = *(const s16x8*)(B + (size_t)colc*K + kb);
    #pragma unroll
    for (int m = 0; m < MT; ++m) {
      s16x8 af = *(const s16x8*)(A + (size_t)arow[m]*astride + kb);
      acc[m] = MFMA16(af, bfv, acc[m]);
    }
  }

  const int r0 = (lane >> 4) * 4;
  #pragma unroll
  for (int m = 0; m < MT; ++m) {
    #pragma unroll
    for (int q = 0; q < 4; ++q) {
      int row = m*16 + r0 + q;
      if (row < M && col < N)
        P[((size_t)ks*M + row)*N + col] = acc[m][q];
    }
  }
}

// ---------------- fused split-K sum + softmax over 512 logits -> bf16 probs into XH[.][1024:1536] ----------------
__global__ __launch_bounds__(256) void k_soft(const float* __restrict__ P, int KS, int M,
                                              unsigned short* __restrict__ dst)  // XH + s*1536 + 1024
{
  __shared__ float sm[512];
  __shared__ float red[8];
  const int m = blockIdx.x;
  const int tid = threadIdx.x, wv = tid>>6, ln = tid&63;
  for (int l = tid; l < 512; l += 256) {
    float s = 0.f;
    for (int ks = 0; ks < KS; ++ks) s += P[((size_t)ks*M + m)*512 + l];
    sm[l] = s;
  }
  __syncthreads();
  float mx = -1e30f;
  for (int l=tid; l<512; l+=256) mx = fmaxf(mx, sm[l]);
  #pragma unroll
  for (int o=32;o;o>>=1) mx = fmaxf(mx, __shfl_xor(mx,o,64));
  if (ln==0) red[wv]=mx;
  __syncthreads();
  mx = fmaxf(fmaxf(red[0],red[1]),fmaxf(red[2],red[3]));
  float se = 0.f;
  for (int l=tid; l<512; l+=256){ float ev=__expf(sm[l]-mx); sm[l]=ev; se+=ev; }
  __syncthreads();
  #pragma unroll
  for (int o=32;o;o>>=1) se += __shfl_xor(se,o,64);
  if (ln==0) red[wv]=se;
  __syncthreads();
  float invS = 1.f/(red[0]+red[1]+red[2]+red[3]);
  for (int l=tid; l<512; l+=256) dst[(size_t)m*1536 + l] = f2bf(sm[l]*invS);
}

// ---------------- et reduction: block per row; tanh; write Etb + scatter to children Xb ----------------
__global__ __launch_bounds__(256) void k_red4(const float* __restrict__ P, int KS, int M,
                                              const float* __restrict__ bias,
                                              unsigned short* __restrict__ Etb, int s,
                                              int snext, unsigned short* __restrict__ XbNext)
{
  const int row = blockIdx.x;
  const int col = threadIdx.x*4;
  float4 sum = *(const float4*)(bias + col);
  for (int ks = 0; ks < KS; ++ks) {
    float4 p = *(const float4*)(P + ((size_t)ks*M + row)*1024 + col);
    sum.x += p.x; sum.y += p.y; sum.z += p.z; sum.w += p.w;
  }
  u16x4 r;
  r[0]=f2bf(tanhfast(sum.x)); r[1]=f2bf(tanhfast(sum.y));
  r[2]=f2bf(tanhfast(sum.z)); r[3]=f2bf(tanhfast(sum.w));
  *(u16x4*)(Etb + (size_t)(s+row)*1024 + col) = r;
  if (XbNext) {
    int cbase = 4*(s+row) + 1;
    #pragma unroll
    for (int k=0;k<4;++k) {
      int cn = cbase + k;
      if (cn < 256) {
        int o = cn - snext;
        *(u16x4*)(XbNext + ((size_t)(o&3)*48 + (o>>2))*2560 + 512 + col) = r;
      }
    }
  }
}

// ---------------- LSTM epilogue: gates -> h,c; scatter h to children Xb ----------------
__global__ __launch_bounds__(256) void k_epi(const float* __restrict__ P,
                                             const float* __restrict__ b_ih, const float* __restrict__ b_hh,
                                             float* __restrict__ Cb, unsigned short* __restrict__ XH,
                                             int s, int snext, unsigned short* __restrict__ XbNext){
  int i = s + blockIdx.x;
  int slot = (i - s) & 3, j = (i - s) >> 2;
  int p = (i - 1) >> 2;
  const float* bi = b_ih + (size_t)slot*4096;
  const float* bh = b_hh + (size_t)slot*4096;
  const int u = threadIdx.x*4;

  float4 ig, fg, gg, og;
  {
    float4 a, b;
    a = *(const float4*)(bi+u);      b = *(const float4*)(bh+u);      ig = make_float4(a.x+b.x,a.y+b.y,a.z+b.z,a.w+b.w);
    a = *(const float4*)(bi+1024+u); b = *(const float4*)(bh+1024+u); fg = make_float4(a.x+b.x,a.y+b.y,a.z+b.z,a.w+b.w);
    a = *(const float4*)(bi+2048+u); b = *(const float4*)(bh+2048+u); gg = make_float4(a.x+b.x,a.y+b.y,a.z+b.z,a.w+b.w);
    a = *(const float4*)(bi+3072+u); b = *(const float4*)(bh+3072+u); og = make_float4(a.x+b.x,a.y+b.y,a.z+b.z,a.w+b.w);
  }
  #pragma unroll
  for (int ks = 0; ks < 5; ++ks) {
    const float* g = P + (((size_t)slot*5 + ks)*48 + j)*4096;
    float4 a;
    a = *(const float4*)(g+u);      ig.x+=a.x; ig.y+=a.y; ig.z+=a.z; ig.w+=a.w;
    a = *(const float4*)(g+1024+u); fg.x+=a.x; fg.y+=a.y; fg.z+=a.z; fg.w+=a.w;
    a = *(const float4*)(g+2048+u); gg.x+=a.x; gg.y+=a.y; gg.z+=a.z; gg.w+=a.w;
    a = *(const float4*)(g+3072+u); og.x+=a.x; og.y+=a.y; og.z+=a.z; og.w+=a.w;
  }
  float4 cp = *(const float4*)(Cb + (size_t)p*1024 + u);
  float4 cc, hh;
  cc.x = sigf(fg.x)*cp.x + sigf(ig.x)*tanhfast(gg.x); hh.x = sigf(og.x)*tanhfast(cc.x);
  cc.y = sigf(fg.y)*cp.y + sigf(ig.y)*tanhfast(gg.y); hh.y = sigf(og.y)*tanhfast(cc.y);
  cc.z = sigf(fg.z)*cp.z + sigf(ig.z)*tanhfast(gg.z); hh.z = sigf(og.z)*tanhfast(cc.z);
  cc.w = sigf(fg.w)*cp.w + sigf(ig.w)*tanhfast(gg.w); hh.w = sigf(og.w)*tanhfast(cc.w);
  *(float4*)(Cb + (size_t)i*1024 + u) = cc;
  u16x4 r; r[0]=f2bf(hh.x); r[1]=f2bf(hh.y); r[2]=f2bf(hh.z); r[3]=f2bf(hh.w);
  *(u16x4*)(XH + (size_t)i*1536 + u) = r;
  if (XbNext) {
    int cbase = 4*i + 1;
    #pragma unroll
    for (int k=0;k<4;++k) {
      int cn = cbase + k;
      if (cn < 256) {
        int o = cn - snext;
        *(u16x4*)(XbNext + ((size_t)(o&3)*48 + (o>>2))*2560 + 1536 + u) = r;
      }
    }
  }
}

// ---------------- loss per node (bf16 logits) ----------------
__global__ __launch_bounds__(256) void k_loss(const unsigned short* __restrict__ Lgb,
                                              const int* __restrict__ values,
                                              float* __restrict__ Nl)
{
  __shared__ float red[8];
  const int node = blockIdx.x;
  const int tid = threadIdx.x, wv = tid>>6, ln = tid&63;
  const unsigned short* lg = Lgb + (size_t)node*NCLS;

  float m = -1e30f;
  for (int i=tid;i<NCLS;i+=256) m = fmaxf(m, bf2f(lg[i]));
  #pragma unroll
  for (int o=32;o;o>>=1) m = fmaxf(m, __shfl_xor(m,o,64));
  if (ln==0) red[wv]=m;
  __syncthreads();
  m = fmaxf(fmaxf(red[0],red[1]),fmaxf(red[2],red[3]));
  __syncthreads();

  float s = 0.f;
  for (int i=tid;i<NCLS;i+=256) s += __expf(bf2f(lg[i])-m);
  #pragma unroll
  for (int o=32;o;o>>=1) s += __shfl_xor(s,o,64);
  if (ln==0) red[wv]=s;
  __syncthreads();
  s = red[0]+red[1]+red[2]+red[3];
  __syncthreads();
  float invs = 1.f/s;

  float q = 0.f;
  for (int i=tid;i<NCLS;i+=256) q += __expf(__expf(bf2f(lg[i])-m)*invs);
  #pragma unroll
  for (int o=32;o;o>>=1) q += __shfl_xor(q,o,64);
  if (ln==0) red[wv]=q;
  __syncthreads();
  if (tid==0) {
    float qq = red[0]+red[1]+red[2]+red[3];
    int v = values[node];
    float pv = __expf(bf2f(lg[v])-m)*invs;
    float nl = __logf(qq) - pv;
    if (v == NCLS-1) nl *= 0.2f;
    Nl[node] = nl;
  }
}

__global__ __launch_bounds__(256) void k_final(const float* __restrict__ Nl, float* __restrict__ out){
  __shared__ float red[8];
  int tid = threadIdx.x, wv = tid>>6, ln = tid&63;
  float s = Nl[tid];
  #pragma unroll
  for (int o=32;o;o>>=1) s += __shfl_xor(s,o,64);
  if (ln==0) red[wv]=s;
  __syncthreads();
  if (tid==0) out[0] = red[0]+red[1]+red[2]+red[3];
}

static inline void gemm_skb(hipStream_t st, int MT, const unsigned short* A, int astride,
                            const unsigned short* B, int K, float* P, int N, int M)
{
  dim3 grid(N/64, K/128);
  #define SKCASE(MTv) k_gemm_skb<MTv><<<grid, 256, 0, st>>>(A,astride,B,K,P,N,M)
  switch(MT){
    case 1:  SKCASE(1);  break;
    case 4:  SKCASE(4);  break;
    case 11: SKCASE(11); break;
    default: SKCASE(16); break;
  }
  #undef SKCASE
}

extern "C" void kernel_launch(void* const* d_in, const int* in_sizes, int n_in,
                              void* d_out, int out_size, void* d_ws, size_t ws_size,
                              hipStream_t stream)
{
  const float* rootH = (const float*)d_in[0];
  const float* rootC = (const float*)d_in[1];
  const float* ann   = (const float*)d_in[2];
  const int*   values= (const int*)d_in[3];
  const float* emb   = (const float*)d_in[6];
  const float* W_ih  = (const float*)d_in[7];
  const float* W_hh  = (const float*)d_in[8];
  const float* b_ih  = (const float*)d_in[9];
  const float* b_hh  = (const float*)d_in[10];
  const float* W_att = (const float*)d_in[11];
  const float* b_att = (const float*)d_in[12];
  const float* W_pre = (const float*)d_in[13];
  const float* b_pre = (const float*)d_in[14];
  const float* W_out = (const float*)d_in[15];
  const float* b_out = (const float*)d_in[16];

  float* ws = (float*)d_ws;
  float* Cb  = ws; ws += 256*1024;              // fp32 c
  float* Nl  = ws; ws += 256;
  float* PB  = ws; ws += 4*5*48*4096;           // shared split-K partials
  unsigned short* Wbih  = (unsigned short*)ws;  // bf16 [4][4096][1536]
  unsigned short* Wbhh  = Wbih  + (size_t)4*4096*1536;   // bf16 [4][4096][1024]
  unsigned short* Wattb = Wbhh  + (size_t)4*4096*1024;   // bf16 [1024][1024]
  unsigned short* Bpre  = Wattb + 1024*1024;    // bf16 [1024][1536] = [W_pre_h | ANWT]
  unsigned short* Wpcb  = Bpre  + 1024*1536;    // bf16 [1024][1024] W_pre ctx half
  unsigned short* AHVb  = Wpcb  + 1024*1024;    // bf16 [512][1024]
  unsigned short* Annb  = AHVb  + 512*1024;     // bf16 [512][1024]
  unsigned short* XH    = Annb  + 512*1024;     // bf16 [256][1536] = [h | probs]
  unsigned short* Etb   = XH    + 256*1536;     // bf16 [256][1024]
  unsigned short* Xb    = Etb   + 256*1024;     // bf16 [4 levels][4][48][2560]
  unsigned short* Lgb   = Xb    + (size_t)4*4*48*2560;   // bf16 [256][10001] logits

  // ---- one-time prep ----
  k_cvtall<<<5568, 256, 0, stream>>>(W_ih, W_hh, ann, W_att, W_pre,
                                     Wbih, Wbhh, Annb, Wattb, Bpre, Wpcb);
  k_emb   <<<255,  64,  0, stream>>>(emb, values, Xb);
  // AHV = ann @ W_att^T + b_att  (bf16 out)
  k_gemm_fb<4><<<dim3(16,8), 256, 0, stream>>>(Annb, 1024, Wattb, 1024, b_att, AHVb, 1024, 0, 1024, 512);
  // ANWT[out][l] = W_pre_ctx[out]·ann[l] -> Bpre[out][1024:1536]
  k_gemm_fb<4><<<dim3(8,16), 256, 0, stream>>>(Wpcb, 1024, Annb, 1024, nullptr, Bpre, 1536, 1024, 512, 1024);
  k_root<<<1, 256, 0, stream>>>(rootH, rootC, Cb, XH, Xb);

  const int LS[6] = {0,1,5,21,85,256};
  for (int lev=0; lev<5; ++lev){
    int s=LS[lev], e=LS[lev+1], n=e-s;
    unsigned short* XbL = Xb + (size_t)(lev-1)*4*48*2560;       // this level's LSTM input (lev>=1)
    unsigned short* XbN = (lev<4) ? (Xb + (size_t)lev*4*48*2560) : nullptr;  // children's
    int snext = (lev<4) ? LS[lev+1] : 0;
    if (lev>0){
      if (lev==4)
        k_gemm_skzb2<3,16><<<dim3(64,5,4),256,0,stream>>>(XbL, 2560, Wbih, 1536, Wbhh, 1024, PB,
            4096, n, 48, 48*2560, 4096*1536, 4096*1024, 5);
      else
        k_gemm_skzb2<1,16><<<dim3(64,5,4),256,0,stream>>>(XbL, 2560, Wbih, 1536, Wbhh, 1024, PB,
            4096, n, 48, 48*2560, 4096*1536, 4096*1024, 5);
      k_epi<<<n,256,0,stream>>>(PB, b_ih, b_hh, Cb, XH, s, snext, XbN);
    }
    int mtn = (n+15)/16;
    // attention logits [n x 512] = h · AHV^T (split-K MFMA) + fused softmax -> probs in XH
    gemm_skb(stream, mtn, XH + (size_t)s*1536, 1536, AHVb, 1024, PB, 512, n);
    k_soft<<<n,256,0,stream>>>(PB, 8, n, XH + (size_t)s*1536 + 1024);
    // et = tanh([h|probs] · Bpre^T + b_pre): split-K + per-row reduce (+ scatter to children Xb)
    gemm_skb(stream, mtn, XH + (size_t)s*1536, 1536, Bpre, 1536, PB, 1024, n);
    k_red4<<<n,256,0,stream>>>(PB, 12, n, b_pre, Etb, s, snext, XbN);
  }

  // W_out logits: fp32 B staged->LDS with convert, bf16 output
  k_wout<<<626, 256, 0, stream>>>(Etb, W_out, b_out, Lgb);
  k_loss <<<256,256,0,stream>>>(Lgb, values, Nl);
  k_final<<<1,  256,0,stream>>>(Nl, (float*)d_out);
}

// Round 14
// 395.409 us; speedup vs baseline: 1.4236x; 1.0360x over previous
//
#include <hip/hip_runtime.h>
#include <hip/hip_bf16.h>
#include <math.h>

#define HD 1024
#define NCLS 10001

typedef short s16x8 __attribute__((ext_vector_type(8)));
typedef unsigned short u16x8 __attribute__((ext_vector_type(8)));
typedef unsigned short u16x4 __attribute__((ext_vector_type(4)));
typedef float f32x4 __attribute__((ext_vector_type(4)));
#define MFMA16(a_, b_, c_) __builtin_amdgcn_mfma_f32_16x16x32_bf16((a_), (b_), (c_), 0, 0, 0)

__device__ __forceinline__ float sigf(float x){ return 1.f/(1.f+__expf(-x)); }
__device__ __forceinline__ float tanhfast(float x){
  x = fminf(fmaxf(x,-10.f),10.f);
  float e2 = __expf(2.f*x);
  return (e2-1.f)/(e2+1.f);
}
__device__ __forceinline__ unsigned short f2bf(float f){
  unsigned int u = __float_as_uint(f);
  u += 0x7FFF + ((u >> 16) & 1);          // round-to-nearest-even
  return (unsigned short)(u >> 16);
}
__device__ __forceinline__ float bf2f(unsigned short u){
  return __uint_as_float(((unsigned)u) << 16);
}
__device__ __forceinline__ u16x8 pack8(float4 a, float4 b){
  u16x8 r;
  r[0]=f2bf(a.x); r[1]=f2bf(a.y); r[2]=f2bf(a.z); r[3]=f2bf(a.w);
  r[4]=f2bf(b.x); r[5]=f2bf(b.y); r[6]=f2bf(b.z); r[7]=f2bf(b.w);
  return r;
}

// ---------------- merged fp32->bf16 conversion (NO W_out) — exact grid, forced-MLP ----------------
#define CN0 25165824u   // W_ih  4*4096*1536
#define CN1 16777216u   // W_hh  4*4096*1024
#define CN3 524288u     // ann   512*1024
#define CN4 1048576u    // W_att 1024*1024
#define CN5 2097152u    // W_pre 1024*2048
#define CTOT2 (CN0+CN1+CN3+CN4+CN5)   // 45613056 = 5568 blocks * 1024 groups * 8 elems exactly
struct SD { const float* s; unsigned short* d; };
__device__ __forceinline__ SD cvt_resolve(unsigned idx,
    const float* Wih, const float* Whh, const float* ann, const float* Watt, const float* Wpre,
    unsigned short* Wbih, unsigned short* Wbhh, unsigned short* Annb, unsigned short* Wattb,
    unsigned short* Bpre, unsigned short* Wpcb)
{
  SD r;
  if (idx < CN0) { r.s = Wih + idx; r.d = Wbih + idx; return r; }
  idx -= CN0;
  if (idx < CN1) { r.s = Whh + idx; r.d = Wbhh + idx; return r; }
  idx -= CN1;
  if (idx < CN3) { r.s = ann + idx; r.d = Annb + idx; return r; }
  idx -= CN3;
  if (idx < CN4) { r.s = Watt + idx; r.d = Wattb + idx; return r; }
  idx -= CN4;
  r.s = Wpre + idx;
  unsigned row = idx >> 11, c = idx & 2047;   // 8-group never straddles the 1024 split
  r.d = (c < 1024) ? (Bpre + (size_t)row*1536 + c) : (Wpcb + (size_t)row*1024 + (c-1024));
  return r;
}
__global__ __launch_bounds__(256) void k_cvtall(
    const float* __restrict__ Wih, const float* __restrict__ Whh,
    const float* __restrict__ ann, const float* __restrict__ Watt, const float* __restrict__ Wpre,
    unsigned short* __restrict__ Wbih, unsigned short* __restrict__ Wbhh,
    unsigned short* __restrict__ Annb, unsigned short* __restrict__ Wattb,
    unsigned short* __restrict__ Bpre, unsigned short* __restrict__ Wpcb)
{
  unsigned g = blockIdx.x*1024u + threadIdx.x;     // 8-elem group index; chunks at +256*it
  SD p0 = cvt_resolve((g        )*8u, Wih,Whh,ann,Watt,Wpre, Wbih,Wbhh,Annb,Wattb,Bpre,Wpcb);
  SD p1 = cvt_resolve((g +  256u)*8u, Wih,Whh,ann,Watt,Wpre, Wbih,Wbhh,Annb,Wattb,Bpre,Wpcb);
  SD p2 = cvt_resolve((g +  512u)*8u, Wih,Whh,ann,Watt,Wpre, Wbih,Wbhh,Annb,Wattb,Bpre,Wpcb);
  SD p3 = cvt_resolve((g +  768u)*8u, Wih,Whh,ann,Watt,Wpre, Wbih,Wbhh,Annb,Wattb,Bpre,Wpcb);
  float4 a0 = *(const float4*)p0.s, b0 = *(const float4*)(p0.s+4);
  float4 a1 = *(const float4*)p1.s, b1 = *(const float4*)(p1.s+4);
  float4 a2 = *(const float4*)p2.s, b2 = *(const float4*)(p2.s+4);
  float4 a3 = *(const float4*)p3.s, b3 = *(const float4*)(p3.s+4);
  __builtin_amdgcn_sched_barrier(0);   // keep all 8 loads issued before packs/stores (MLP)
  *(u16x8*)p0.d = pack8(a0,b0);
  *(u16x8*)p1.d = pack8(a1,b1);
  *(u16x8*)p2.d = pack8(a2,b2);
  *(u16x8*)p3.d = pack8(a3,b3);
}

// ---------------- emb halves of all LSTM inputs (one-shot; tree topology is static) ----------------
__global__ __launch_bounds__(64) void k_emb(const float* __restrict__ emb, const int* __restrict__ values,
                                            unsigned short* __restrict__ Xb){
  int i = blockIdx.x + 1;                  // 1..255
  int lev, s;
  if (i < 5)       { lev=1; s=1; }
  else if (i < 21) { lev=2; s=5; }
  else if (i < 85) { lev=3; s=21; }
  else             { lev=4; s=85; }
  int p = (i-1)>>2, o = i - s;
  unsigned short* xr = Xb + ((size_t)(lev-1)*4*48 + (size_t)(o&3)*48 + (o>>2)) * 2560;
  const float* er = emb + (size_t)values[p]*512;
  int c = threadIdx.x*8;
  float4 a = *(const float4*)(er+c), b = *(const float4*)(er+c+4);
  *(u16x8*)(xr+c) = pack8(a,b);
}

// ---------------- root: C, XH h, and h into level-1 child slots ----------------
__global__ __launch_bounds__(256) void k_root(const float* __restrict__ rH, const float* __restrict__ rC,
                                              float* __restrict__ Cb, unsigned short* __restrict__ XH,
                                              unsigned short* __restrict__ Xb1){
  int u = threadIdx.x*4;
  float4 h = *(const float4*)(rH+u);
  float4 c = *(const float4*)(rC+u);
  *(float4*)(Cb+u) = c;
  u16x4 r; r[0]=f2bf(h.x); r[1]=f2bf(h.y); r[2]=f2bf(h.z); r[3]=f2bf(h.w);
  *(u16x4*)(XH+u) = r;
  #pragma unroll
  for (int k=0;k<4;++k)
    *(u16x4*)(Xb1 + (size_t)k*48*2560 + 1536 + u) = r;
}

// ---------------- full-K bf16 GEMM (AHV / ANWT prep) ----------------
template<int MT>
__global__ __launch_bounds__(256) void k_gemm_fb(
    const unsigned short* __restrict__ A, int astride,
    const unsigned short* __restrict__ B, int K,
    const float* __restrict__ bias,
    unsigned short* __restrict__ Cb16,
    int ostride, int coff, int N, int M)
{
  const int mb0 = blockIdx.y * (MT*16);
  const int wv = threadIdx.x >> 6, lane = threadIdx.x & 63;
  const int col = (blockIdx.x*4 + wv)*16 + (lane & 15);
  const int colc = min(col, N-1);
  const int khalf = (lane >> 4) * 8;

  f32x4 acc[MT];
  #pragma unroll
  for (int m = 0; m < MT; ++m) acc[m] = (f32x4){0.f,0.f,0.f,0.f};
  int arow[MT];
  #pragma unroll
  for (int m = 0; m < MT; ++m) arow[m] = min(mb0 + m*16 + (lane & 15), M-1);

  #pragma unroll 4
  for (int kk = 0; kk < K; kk += 32) {
    int kb = kk + khalf;
    s16x8 bfv = *(const s16x8*)(B + (size_t)colc*K + kb);
    #pragma unroll
    for (int m = 0; m < MT; ++m) {
      s16x8 af = *(const s16x8*)(A + (size_t)arow[m]*astride + kb);
      acc[m] = MFMA16(af, bfv, acc[m]);
    }
  }

  const int r0 = (lane >> 4) * 4;
  #pragma unroll
  for (int m = 0; m < MT; ++m) {
    #pragma unroll
    for (int q = 0; q < 4; ++q) {
      int row = mb0 + m*16 + r0 + q;
      if (row < M && col < N) {
        float v = acc[m][q] + (bias ? bias[col] : 0.f);
        Cb16[(size_t)row*ostride + col + coff] = f2bf(v);
      }
    }
  }
}

// ---------------- W_out GEMM: fp32 B staged+converted to LDS (row-clamped, no OOB) ----------------
__global__ __launch_bounds__(256) void k_wout(
    const unsigned short* __restrict__ A,      // Etb [256][1024]
    const float* __restrict__ B,               // W_out fp32 [10001][1024]
    const float* __restrict__ bias,
    unsigned short* __restrict__ Lgb)
{
  __shared__ unsigned short bs[16*1032];
  const int c0 = blockIdx.x*16;
  const int tid = threadIdx.x;
  #pragma unroll
  for (int it = 0; it < 8; ++it) {
    int e = it*2048 + tid*8;
    int row = e >> 10, ck = e & 1023;
    int rr = min(c0 + row, NCLS-1);
    const float* sp = B + (size_t)rr*1024 + ck;
    float4 a = *(const float4*)sp, b = *(const float4*)(sp+4);
    *(u16x8*)(bs + row*1032 + ck) = pack8(a,b);
  }
  __syncthreads();

  const int wv = tid >> 6, lane = tid & 63;
  const int col16 = lane & 15;
  const int khalf = (lane >> 4) * 8;
  const int mb0 = wv * 64;
  const int col = c0 + col16;

  f32x4 acc[4];
  #pragma unroll
  for (int m=0;m<4;++m) acc[m] = (f32x4){0.f,0.f,0.f,0.f};
  int arow[4];
  #pragma unroll
  for (int m=0;m<4;++m) arow[m] = mb0 + m*16 + col16;

  #pragma unroll 8
  for (int kk = 0; kk < 1024; kk += 32) {
    int kb = kk + khalf;
    s16x8 bfv = *(const s16x8*)(bs + col16*1032 + kb);
    #pragma unroll
    for (int m=0;m<4;++m) {
      s16x8 af = *(const s16x8*)(A + (size_t)arow[m]*1024 + kb);
      acc[m] = MFMA16(af, bfv, acc[m]);
    }
  }

  if (col < NCLS) {
    const int r0 = (lane >> 4) * 4;
    float bv = bias[col];
    #pragma unroll
    for (int m=0;m<4;++m) {
      #pragma unroll
      for (int q=0;q<4;++q) {
        int row = mb0 + m*16 + r0 + q;
        Lgb[(size_t)row*NCLS + col] = f2bf(acc[m][q] + bv);
      }
    }
  }
}

// ---------------- split-K + slot-batched bf16 GEMM (LSTM), B split B1|B2 ----------------
template<int MT, int KITER>
__global__ __launch_bounds__(256) void k_gemm_skzb2(
    const unsigned short* __restrict__ A, int astride,
    const unsigned short* __restrict__ B1, int K1,
    const unsigned short* __restrict__ B2, int K2,
    float* __restrict__ P, int N, int Mbase, int Mpad,
    int aZ, int b1Z, int b2Z, int KS)
{
  const int z = blockIdx.z;
  const int M = (Mbase - z + 3) >> 2;
  const unsigned short* Az = A + (size_t)z*aZ;
  const unsigned short* B1z = B1 + (size_t)z*b1Z;
  const unsigned short* B2z = B2 + (size_t)z*b2Z;
  const int ks = blockIdx.y;
  const int k0 = ks * (KITER*32);
  const int wv = threadIdx.x >> 6, lane = threadIdx.x & 63;
  const int col = (blockIdx.x*4 + wv)*16 + (lane & 15);
  const int colc = min(col, N-1);
  const int khalf = (lane >> 4) * 8;

  f32x4 acc[MT];
  #pragma unroll
  for (int m = 0; m < MT; ++m) acc[m] = (f32x4){0.f,0.f,0.f,0.f};
  int arow[MT];
  #pragma unroll
  for (int m = 0; m < MT; ++m) arow[m] = min(m*16 + (lane & 15), M-1);

  #pragma unroll 8
  for (int kk = 0; kk < KITER*32; kk += 32) {
    int kb = k0 + kk + khalf;
    const unsigned short* bp = (kb < K1) ? (B1z + (size_t)colc*K1 + kb)
                                         : (B2z + (size_t)colc*K2 + (kb - K1));
    s16x8 bfv = *(const s16x8*)bp;
    #pragma unroll
    for (int m = 0; m < MT; ++m) {
      s16x8 af = *(const s16x8*)(Az + (size_t)arow[m]*astride + kb);
      acc[m] = MFMA16(af, bfv, acc[m]);
    }
  }

  const int r0 = (lane >> 4) * 4;
  #pragma unroll
  for (int m = 0; m < MT; ++m) {
    #pragma unroll
    for (int q = 0; q < 4; ++q) {
      int row = m*16 + r0 + q;
      if (row < M && col < N)
        P[(((size_t)z*KS + ks)*Mpad + row)*N + col] = acc[m][q];
    }
  }
}

// ---------------- small split-K bf16 GEMM (chunk 128): P[ks][M][N] ----------------
template<int MT>
__global__ __launch_bounds__(256) void k_gemm_skb(
    const unsigned short* __restrict__ A, int astride,
    const unsigned short* __restrict__ B, int K,
    float* __restrict__ P, int N, int M)
{
  const int ks = blockIdx.y;
  const int k0 = ks * 128;
  const int wv = threadIdx.x >> 6, lane = threadIdx.x & 63;
  const int col = (blockIdx.x*4 + wv)*16 + (lane & 15);
  const int colc = min(col, N-1);
  const int khalf = (lane >> 4) * 8;

  f32x4 acc[MT];
  #pragma unroll
  for (int m = 0; m < MT; ++m) acc[m] = (f32x4){0.f,0.f,0.f,0.f};
  int arow[MT];
  #pragma unroll
  for (int m = 0; m < MT; ++m) arow[m] = min(m*16 + (lane & 15), M-1);

  #pragma unroll
  for (int kk = 0; kk < 128; kk += 32) {
    int kb = k0 + kk + khalf;
    s16x8 bfv = *(const s16x8*)(B + (size_t)colc*K + kb);
    #pragma unroll
    for (int m = 0; m < MT; ++m) {
      s16x8 af = *(const s16x8*)(A + (size_t)arow[m]*astride + kb);
      acc[m] = MFMA16(af, bfv, acc[m]);
    }
  }

  const int r0 = (lane >> 4) * 4;
  #pragma unroll
  for (int m = 0; m < MT; ++m) {
    #pragma unroll
    for (int q = 0; q < 4; ++q) {
      int row = m*16 + r0 + q;
      if (row < M && col < N)
        P[((size_t)ks*M + row)*N + col] = acc[m][q];
    }
  }
}

// ---------------- fused split-K sum + softmax over 512 logits -> bf16 probs into XH[.][1024:1536] ----------------
__global__ __launch_bounds__(256) void k_soft(const float* __restrict__ P, int KS, int M,
                                              unsigned short* __restrict__ dst)  // XH + s*1536 + 1024
{
  __shared__ float sm[512];
  __shared__ float red[8];
  const int m = blockIdx.x;
  const int tid = threadIdx.x, wv = tid>>6, ln = tid&63;
  for (int l = tid; l < 512; l += 256) {
    float s = 0.f;
    for (int ks = 0; ks < KS; ++ks) s += P[((size_t)ks*M + m)*512 + l];
    sm[l] = s;
  }
  __syncthreads();
  float mx = -1e30f;
  for (int l=tid; l<512; l+=256) mx = fmaxf(mx, sm[l]);
  #pragma unroll
  for (int o=32;o;o>>=1) mx = fmaxf(mx, __shfl_xor(mx,o,64));
  if (ln==0) red[wv]=mx;
  __syncthreads();
  mx = fmaxf(fmaxf(red[0],red[1]),fmaxf(red[2],red[3]));
  float se = 0.f;
  for (int l=tid; l<512; l+=256){ float ev=__expf(sm[l]-mx); sm[l]=ev; se+=ev; }
  __syncthreads();
  #pragma unroll
  for (int o=32;o;o>>=1) se += __shfl_xor(se,o,64);
  if (ln==0) red[wv]=se;
  __syncthreads();
  float invS = 1.f/(red[0]+red[1]+red[2]+red[3]);
  for (int l=tid; l<512; l+=256) dst[(size_t)m*1536 + l] = f2bf(sm[l]*invS);
}

// ---------------- et reduction: block per row; tanh; write Etb + scatter to children Xb ----------------
__global__ __launch_bounds__(256) void k_red4(const float* __restrict__ P, int KS, int M,
                                              const float* __restrict__ bias,
                                              unsigned short* __restrict__ Etb, int s,
                                              int snext, unsigned short* __restrict__ XbNext)
{
  const int row = blockIdx.x;
  const int col = threadIdx.x*4;
  float4 sum = *(const float4*)(bias + col);
  for (int ks = 0; ks < KS; ++ks) {
    float4 p = *(const float4*)(P + ((size_t)ks*M + row)*1024 + col);
    sum.x += p.x; sum.y += p.y; sum.z += p.z; sum.w += p.w;
  }
  u16x4 r;
  r[0]=f2bf(tanhfast(sum.x)); r[1]=f2bf(tanhfast(sum.y));
  r[2]=f2bf(tanhfast(sum.z)); r[3]=f2bf(tanhfast(sum.w));
  *(u16x4*)(Etb + (size_t)(s+row)*1024 + col) = r;
  if (XbNext) {
    int cbase = 4*(s+row) + 1;
    #pragma unroll
    for (int k=0;k<4;++k) {
      int cn = cbase + k;
      if (cn < 256) {
        int o = cn - snext;
        *(u16x4*)(XbNext + ((size_t)(o&3)*48 + (o>>2))*2560 + 512 + col) = r;
      }
    }
  }
}

// ---------------- LSTM epilogue: gates -> h,c; scatter h to children Xb ----------------
__global__ __launch_bounds__(256) void k_epi(const float* __restrict__ P,
                                             const float* __restrict__ b_ih, const float* __restrict__ b_hh,
                                             float* __restrict__ Cb, unsigned short* __restrict__ XH,
                                             int s, int snext, unsigned short* __restrict__ XbNext){
  int i = s + blockIdx.x;
  int slot = (i - s) & 3, j = (i - s) >> 2;
  int p = (i - 1) >> 2;
  const float* bi = b_ih + (size_t)slot*4096;
  const float* bh = b_hh + (size_t)slot*4096;
  const int u = threadIdx.x*4;

  float4 ig, fg, gg, og;
  {
    float4 a, b;
    a = *(const float4*)(bi+u);      b = *(const float4*)(bh+u);      ig = make_float4(a.x+b.x,a.y+b.y,a.z+b.z,a.w+b.w);
    a = *(const float4*)(bi+1024+u); b = *(const float4*)(bh+1024+u); fg = make_float4(a.x+b.x,a.y+b.y,a.z+b.z,a.w+b.w);
    a = *(const float4*)(bi+2048+u); b = *(const float4*)(bh+2048+u); gg = make_float4(a.x+b.x,a.y+b.y,a.z+b.z,a.w+b.w);
    a = *(const float4*)(bi+3072+u); b = *(const float4*)(bh+3072+u); og = make_float4(a.x+b.x,a.y+b.y,a.z+b.z,a.w+b.w);
  }
  #pragma unroll
  for (int ks = 0; ks < 5; ++ks) {
    const float* g = P + (((size_t)slot*5 + ks)*48 + j)*4096;
    float4 a;
    a = *(const float4*)(g+u);      ig.x+=a.x; ig.y+=a.y; ig.z+=a.z; ig.w+=a.w;
    a = *(const float4*)(g+1024+u); fg.x+=a.x; fg.y+=a.y; fg.z+=a.z; fg.w+=a.w;
    a = *(const float4*)(g+2048+u); gg.x+=a.x; gg.y+=a.y; gg.z+=a.z; gg.w+=a.w;
    a = *(const float4*)(g+3072+u); og.x+=a.x; og.y+=a.y; og.z+=a.z; og.w+=a.w;
  }
  float4 cp = *(const float4*)(Cb + (size_t)p*1024 + u);
  float4 cc, hh;
  cc.x = sigf(fg.x)*cp.x + sigf(ig.x)*tanhfast(gg.x); hh.x = sigf(og.x)*tanhfast(cc.x);
  cc.y = sigf(fg.y)*cp.y + sigf(ig.y)*tanhfast(gg.y); hh.y = sigf(og.y)*tanhfast(cc.y);
  cc.z = sigf(fg.z)*cp.z + sigf(ig.z)*tanhfast(gg.z); hh.z = sigf(og.z)*tanhfast(cc.z);
  cc.w = sigf(fg.w)*cp.w + sigf(ig.w)*tanhfast(gg.w); hh.w = sigf(og.w)*tanhfast(cc.w);
  *(float4*)(Cb + (size_t)i*1024 + u) = cc;
  u16x4 r; r[0]=f2bf(hh.x); r[1]=f2bf(hh.y); r[2]=f2bf(hh.z); r[3]=f2bf(hh.w);
  *(u16x4*)(XH + (size_t)i*1536 + u) = r;
  if (XbNext) {
    int cbase = 4*i + 1;
    #pragma unroll
    for (int k=0;k<4;++k) {
      int cn = cbase + k;
      if (cn < 256) {
        int o = cn - snext;
        *(u16x4*)(XbNext + ((size_t)(o&3)*48 + (o>>2))*2560 + 1536 + u) = r;
      }
    }
  }
}

// ---------------- loss per node (bf16 logits, register-cached single read) ----------------
__global__ __launch_bounds__(256) void k_loss(const unsigned short* __restrict__ Lgb,
                                              const int* __restrict__ values,
                                              float* __restrict__ Nl)
{
  __shared__ float red[8];
  const int node = blockIdx.x;
  const int tid = threadIdx.x, wv = tid>>6, ln = tid&63;
  const unsigned short* lg = Lgb + (size_t)node*NCLS;

  // load all logits once: chunks j=0..3 full (base<8192), j=4 tail padded with bf16 -inf (0xFF80)
  u16x8 v0 = *(const u16x8*)(lg + 0*2048 + tid*8);
  u16x8 v1 = *(const u16x8*)(lg + 1*2048 + tid*8);
  u16x8 v2 = *(const u16x8*)(lg + 2*2048 + tid*8);
  u16x8 v3 = *(const u16x8*)(lg + 3*2048 + tid*8);
  u16x8 v4;
  {
    int e = 8192 + tid*8;
    #pragma unroll
    for (int k=0;k<8;++k) v4[k] = (e+k < NCLS) ? lg[e+k] : (unsigned short)0xFF80;
  }

  float m = -1e30f;
  #pragma unroll
  for (int k=0;k<8;++k){
    m = fmaxf(m, bf2f(v0[k])); m = fmaxf(m, bf2f(v1[k]));
    m = fmaxf(m, bf2f(v2[k])); m = fmaxf(m, bf2f(v3[k]));
    m = fmaxf(m, bf2f(v4[k]));
  }
  #pragma unroll
  for (int o=32;o;o>>=1) m = fmaxf(m, __shfl_xor(m,o,64));
  if (ln==0) red[wv]=m;
  __syncthreads();
  m = fmaxf(fmaxf(red[0],red[1]),fmaxf(red[2],red[3]));
  __syncthreads();

  float s = 0.f;
  #pragma unroll
  for (int k=0;k<8;++k){
    s += __expf(bf2f(v0[k])-m); s += __expf(bf2f(v1[k])-m);
    s += __expf(bf2f(v2[k])-m); s += __expf(bf2f(v3[k])-m);
    s += __expf(bf2f(v4[k])-m);   // pad -inf -> 0
  }
  #pragma unroll
  for (int o=32;o;o>>=1) s += __shfl_xor(s,o,64);
  if (ln==0) red[wv]=s;
  __syncthreads();
  s = red[0]+red[1]+red[2]+red[3];
  __syncthreads();
  float invs = 1.f/s;

  float q = 0.f;
  #pragma unroll
  for (int k=0;k<8;++k){
    q += __expf(__expf(bf2f(v0[k])-m)*invs);
    q += __expf(__expf(bf2f(v1[k])-m)*invs);
    q += __expf(__expf(bf2f(v2[k])-m)*invs);
    q += __expf(__expf(bf2f(v3[k])-m)*invs);
    if (8192 + tid*8 + k < NCLS) q += __expf(__expf(bf2f(v4[k])-m)*invs);
  }
  #pragma unroll
  for (int o=32;o;o>>=1) q += __shfl_xor(q,o,64);
  if (ln==0) red[wv]=q;
  __syncthreads();
  if (tid==0) {
    float qq = red[0]+red[1]+red[2]+red[3];
    int v = values[node];
    float pv = __expf(bf2f(lg[v])-m)*invs;
    float nl = __logf(qq) - pv;
    if (v == NCLS-1) nl *= 0.2f;
    Nl[node] = nl;
  }
}

__global__ __launch_bounds__(256) void k_final(const float* __restrict__ Nl, float* __restrict__ out){
  __shared__ float red[8];
  int tid = threadIdx.x, wv = tid>>6, ln = tid&63;
  float s = Nl[tid];
  #pragma unroll
  for (int o=32;o;o>>=1) s += __shfl_xor(s,o,64);
  if (ln==0) red[wv]=s;
  __syncthreads();
  if (tid==0) out[0] = red[0]+red[1]+red[2]+red[3];
}

static inline void gemm_skb(hipStream_t st, int MT, const unsigned short* A, int astride,
                            const unsigned short* B, int K, float* P, int N, int M)
{
  dim3 grid(N/64, K/128);
  #define SKCASE(MTv) k_gemm_skb<MTv><<<grid, 256, 0, st>>>(A,astride,B,K,P,N,M)
  switch(MT){
    case 1:  SKCASE(1);  break;
    case 4:  SKCASE(4);  break;
    case 11: SKCASE(11); break;
    default: SKCASE(16); break;
  }
  #undef SKCASE
}

extern "C" void kernel_launch(void* const* d_in, const int* in_sizes, int n_in,
                              void* d_out, int out_size, void* d_ws, size_t ws_size,
                              hipStream_t stream)
{
  const float* rootH = (const float*)d_in[0];
  const float* rootC = (const float*)d_in[1];
  const float* ann   = (const float*)d_in[2];
  const int*   values= (const int*)d_in[3];
  const float* emb   = (const float*)d_in[6];
  const float* W_ih  = (const float*)d_in[7];
  const float* W_hh  = (const float*)d_in[8];
  const float* b_ih  = (const float*)d_in[9];
  const float* b_hh  = (const float*)d_in[10];
  const float* W_att = (const float*)d_in[11];
  const float* b_att = (const float*)d_in[12];
  const float* W_pre = (const float*)d_in[13];
  const float* b_pre = (const float*)d_in[14];
  const float* W_out = (const float*)d_in[15];
  const float* b_out = (const float*)d_in[16];

  float* ws = (float*)d_ws;
  float* Cb  = ws; ws += 256*1024;              // fp32 c
  float* Nl  = ws; ws += 256;
  float* PB  = ws; ws += 4*5*48*4096;           // shared split-K partials
  unsigned short* Wbih  = (unsigned short*)ws;  // bf16 [4][4096][1536]
  unsigned short* Wbhh  = Wbih  + (size_t)4*4096*1536;   // bf16 [4][4096][1024]
  unsigned short* Wattb = Wbhh  + (size_t)4*4096*1024;   // bf16 [1024][1024]
  unsigned short* Bpre  = Wattb + 1024*1024;    // bf16 [1024][1536] = [W_pre_h | ANWT]
  unsigned short* Wpcb  = Bpre  + 1024*1536;    // bf16 [1024][1024] W_pre ctx half
  unsigned short* AHVb  = Wpcb  + 1024*1024;    // bf16 [512][1024]
  unsigned short* Annb  = AHVb  + 512*1024;     // bf16 [512][1024]
  unsigned short* XH    = Annb  + 512*1024;     // bf16 [256][1536] = [h | probs]
  unsigned short* Etb   = XH    + 256*1536;     // bf16 [256][1024]
  unsigned short* Xb    = Etb   + 256*1024;     // bf16 [4 levels][4][48][2560]
  unsigned short* Lgb   = Xb    + (size_t)4*4*48*2560;   // bf16 [256][10001] logits

  // ---- one-time prep ----
  k_cvtall<<<5568, 256, 0, stream>>>(W_ih, W_hh, ann, W_att, W_pre,
                                     Wbih, Wbhh, Annb, Wattb, Bpre, Wpcb);
  k_emb   <<<255,  64,  0, stream>>>(emb, values, Xb);
  // AHV = ann @ W_att^T + b_att  (bf16 out)
  k_gemm_fb<4><<<dim3(16,8), 256, 0, stream>>>(Annb, 1024, Wattb, 1024, b_att, AHVb, 1024, 0, 1024, 512);
  // ANWT[out][l] = W_pre_ctx[out]·ann[l] -> Bpre[out][1024:1536]
  k_gemm_fb<4><<<dim3(8,16), 256, 0, stream>>>(Wpcb, 1024, Annb, 1024, nullptr, Bpre, 1536, 1024, 512, 1024);
  k_root<<<1, 256, 0, stream>>>(rootH, rootC, Cb, XH, Xb);

  const int LS[6] = {0,1,5,21,85,256};
  for (int lev=0; lev<5; ++lev){
    int s=LS[lev], e=LS[lev+1], n=e-s;
    unsigned short* XbL = Xb + (size_t)(lev-1)*4*48*2560;       // this level's LSTM input (lev>=1)
    unsigned short* XbN = (lev<4) ? (Xb + (size_t)lev*4*48*2560) : nullptr;  // children's
    int snext = (lev<4) ? LS[lev+1] : 0;
    if (lev>0){
      if (lev==4)
        k_gemm_skzb2<3,16><<<dim3(64,5,4),256,0,stream>>>(XbL, 2560, Wbih, 1536, Wbhh, 1024, PB,
            4096, n, 48, 48*2560, 4096*1536, 4096*1024, 5);
      else
        k_gemm_skzb2<1,16><<<dim3(64,5,4),256,0,stream>>>(XbL, 2560, Wbih, 1536, Wbhh, 1024, PB,
            4096, n, 48, 48*2560, 4096*1536, 4096*1024, 5);
      k_epi<<<n,256,0,stream>>>(PB, b_ih, b_hh, Cb, XH, s, snext, XbN);
    }
    int mtn = (n+15)/16;
    // attention logits [n x 512] = h · AHV^T (split-K MFMA) + fused softmax -> probs in XH
    gemm_skb(stream, mtn, XH + (size_t)s*1536, 1536, AHVb, 1024, PB, 512, n);
    k_soft<<<n,256,0,stream>>>(PB, 8, n, XH + (size_t)s*1536 + 1024);
    // et = tanh([h|probs] · Bpre^T + b_pre): split-K + per-row reduce (+ scatter to children Xb)
    gemm_skb(stream, mtn, XH + (size_t)s*1536, 1536, Bpre, 1536, PB, 1024, n);
    k_red4<<<n,256,0,stream>>>(PB, 12, n, b_pre, Etb, s, snext, XbN);
  }

  // W_out logits: fp32 B staged->LDS with convert, bf16 output
  k_wout<<<626, 256, 0, stream>>>(Etb, W_out, b_out, Lgb);
  k_loss <<<256,256,0,stream>>>(Lgb, values, Nl);
  k_final<<<1,  256,0,stream>>>(Nl, (float*)d_out);
}